// Round 6
// baseline (1076.216 us; speedup 1.0000x reference)
//
#include <hip/hip_runtime.h>

#define BATCH 2
#define SEQ 512
#define DMODEL 512
#define DINNER 1024
#define DSTATE 16
#define DTRANK 32
#define NBL (BATCH*SEQ)      // 1024
#define EPSV 1e-5f

typedef __attribute__((ext_vector_type(8))) short bf16x8;
typedef __attribute__((ext_vector_type(4))) float f32x4;

static __device__ __forceinline__ float sigmoidf_(float x) {
  return 1.0f / (1.0f + __expf(-x));
}
static __device__ __forceinline__ float softplusf_(float x) {
  return fmaxf(x, 0.0f) + log1pf(__expf(-fabsf(x)));
}
static __device__ __forceinline__ unsigned short f2bf(float x) {
  unsigned int u = __float_as_uint(x);
  unsigned int r = (u + 0x7FFFu + ((u >> 16) & 1u)) >> 16;
  return (unsigned short)r;
}

#define DPPADD(v, ctrl)                                                     \
  v += __int_as_float(__builtin_amdgcn_update_dpp(                          \
      0, __float_as_int(v), ctrl, 0xf, 0xf, true))

// ---------------- all-weight fp32 -> bf16 convert (segmented) ----------------
// segments: in_proj(4.19M), out_w(2.10M), xpw_f(256K), xpw_r(256K),
// dtw_f(128K), dtw_r(128K); all sizes divisible by 2048.
__global__ __launch_bounds__(256) void wconvert_kernel(
    const float* __restrict__ s0, const float* __restrict__ s1,
    const float* __restrict__ s2, const float* __restrict__ s3,
    const float* __restrict__ s4, const float* __restrict__ s5,
    unsigned short* __restrict__ d0, unsigned short* __restrict__ d1,
    unsigned short* __restrict__ d2, unsigned short* __restrict__ d3,
    unsigned short* __restrict__ d4, unsigned short* __restrict__ d5) {
  long i = (long)(blockIdx.x * 256 + threadIdx.x) * 8;
  const float* src; unsigned short* dst;
  if (i < 4194304)      { src = s0; dst = d0; }
  else if (i < 6291456) { src = s1; dst = d1; i -= 4194304; }
  else if (i < 6553600) { src = s2; dst = d2; i -= 6291456; }
  else if (i < 6815744) { src = s3; dst = d3; i -= 6553600; }
  else if (i < 6946816) { src = s4; dst = d4; i -= 6815744; }
  else                  { src = s5; dst = d5; i -= 6946816; }
  const float4 v0 = *(const float4*)&src[i];
  const float4 v1 = *(const float4*)&src[i + 4];
  bf16x8 o;
  o[0] = (short)f2bf(v0.x); o[1] = (short)f2bf(v0.y);
  o[2] = (short)f2bf(v0.z); o[3] = (short)f2bf(v0.w);
  o[4] = (short)f2bf(v1.x); o[5] = (short)f2bf(v1.y);
  o[6] = (short)f2bf(v1.z); o[7] = (short)f2bf(v1.w);
  *(bf16x8*)&dst[i] = o;
}

// ---------------- fused add + RMSNorm ----------------
__global__ __launch_bounds__(256) void addnorm_kernel(
    const float* __restrict__ hs, float* __restrict__ residual,
    const float* __restrict__ w, float* __restrict__ out,
    unsigned short* __restrict__ outb, int first) {
  const int row = blockIdx.x;
  const int t = threadIdx.x;
  const float* hp = hs + (long)row * DMODEL;
  float* rp = residual + (long)row * DMODEL;
  float r0 = hp[t], r1 = hp[t + 256];
  if (!first) { r0 += rp[t]; r1 += rp[t + 256]; }
  rp[t] = r0; rp[t + 256] = r1;
  float ss = r0 * r0 + r1 * r1;
  #pragma unroll
  for (int off = 32; off; off >>= 1) ss += __shfl_xor(ss, off, 64);
  __shared__ float sw[4];
  const int wid = t >> 6, lane = t & 63;
  if (lane == 0) sw[wid] = ss;
  __syncthreads();
  const float tot = sw[0] + sw[1] + sw[2] + sw[3];
  const float scale = rsqrtf(tot * (1.0f / (float)DMODEL) + EPSV);
  const float v0 = r0 * scale * w[t];
  const float v1 = r1 * scale * w[t + 256];
  if (out) {
    out[(long)row * DMODEL + t] = v0;
    out[(long)row * DMODEL + t + 256] = v1;
  }
  if (outb) {
    outb[(long)row * DMODEL + t] = f2bf(v0);
    outb[(long)row * DMODEL + t + 256] = f2bf(v1);
  }
}

#define LDK 40

// ---------------- in_proj GEMM: 128M x 64N tile, grid (16,16) ----------------
// A (2048,512) bf16, B = hnb (1024,512) bf16. C = xz (e, n): C[m*1024 + n].
__global__ __launch_bounds__(256) void gemm_in_kernel(
    const unsigned short* __restrict__ A, const unsigned short* __restrict__ B,
    float* __restrict__ C) {
  __shared__ unsigned short As[128 * LDK];
  __shared__ unsigned short Bs[64 * LDK];
  const int t = threadIdx.x;
  const int m0 = blockIdx.y * 128, n0 = blockIdx.x * 64;
  const int lane = t & 63;
  const int w = t >> 6;
  const int wr = (w >> 1) * 64, wc = (w & 1) * 32;
  const int fr = lane & 15;
  const int fq = lane >> 4;
  const int K = DMODEL;

  f32x4 acc[4][2];
  #pragma unroll
  for (int i = 0; i < 4; ++i)
    #pragma unroll
    for (int j = 0; j < 2; ++j) {
      f32x4 z = {0.f, 0.f, 0.f, 0.f};
      acc[i][j] = z;
    }

  const int srow = t >> 1, sko = (t & 1) * 16;   // A: 128 x 32
  const int brow = t >> 2, bko = (t & 3) * 8;    // B: 64 x 32

  for (int k0 = 0; k0 < K; k0 += 32) {
    if (k0) __syncthreads();
    *(bf16x8*)&As[srow * LDK + sko] =
        *(const bf16x8*)&A[(long)(m0 + srow) * K + k0 + sko];
    *(bf16x8*)&As[srow * LDK + sko + 8] =
        *(const bf16x8*)&A[(long)(m0 + srow) * K + k0 + sko + 8];
    *(bf16x8*)&Bs[brow * LDK + bko] =
        *(const bf16x8*)&B[(long)(n0 + brow) * K + k0 + bko];
    __syncthreads();
    bf16x8 af[4], bg[2];
    #pragma unroll
    for (int i = 0; i < 4; ++i)
      af[i] = *(const bf16x8*)&As[(wr + i * 16 + fr) * LDK + fq * 8];
    #pragma unroll
    for (int j = 0; j < 2; ++j)
      bg[j] = *(const bf16x8*)&Bs[(wc + j * 16 + fr) * LDK + fq * 8];
    #pragma unroll
    for (int i = 0; i < 4; ++i)
      #pragma unroll
      for (int j = 0; j < 2; ++j)
        acc[i][j] = __builtin_amdgcn_mfma_f32_16x16x32_bf16(
            af[i], bg[j], acc[i][j], 0, 0, 0);
  }

  #pragma unroll
  for (int i = 0; i < 4; ++i)
    #pragma unroll
    for (int j = 0; j < 2; ++j)
      #pragma unroll
      for (int r2 = 0; r2 < 4; ++r2) {
        const int m = m0 + wr + i * 16 + fq * 4 + r2;
        const int n = n0 + wc + j * 16 + fr;
        C[(long)m * NBL + n] = acc[i][j][r2];
      }
}

// ---------------- conv+SiLU + transposed bf16 out (fused xct) ----------------
// grid (NBL/32, DINNER/32, 2). Writes xconv fp32 (d,n) and xcT bf16 (dir,n,d).
__global__ __launch_bounds__(256) void conv_silu_kernel(
    const float* __restrict__ xz,
    const float* __restrict__ cw_f, const float* __restrict__ cb_f,
    const float* __restrict__ cw_r, const float* __restrict__ cb_r,
    float* __restrict__ xconv_f, float* __restrict__ xconv_r,
    unsigned short* __restrict__ xcT) {
  __shared__ unsigned short tile[32][33];
  const int dir = blockIdx.z;
  const int n0 = blockIdx.x * 32, d0 = blockIdx.y * 32;
  const int b = n0 >> 9;
  const int l0 = n0 & (SEQ - 1);
  const float* cw = dir ? cw_r : cw_f;
  const float* cb = dir ? cb_r : cb_f;
  float* xconv = dir ? xconv_r : xconv_f;
  unsigned short* dst = xcT + (long)dir * DINNER * NBL;
  const int t = threadIdx.x;
  const int c = t & 31, rr = t >> 5;
  #pragma unroll
  for (int p = 0; p < 4; ++p) {
    const int d = d0 + p * 8 + rr;
    const int l = l0 + c;
    const float* xi = xz + (long)d * NBL + b * SEQ;
    float sum = cb[d];
    #pragma unroll
    for (int k = 0; k < 4; ++k) {
      const int tt = l - 3 + k;
      if (tt >= 0) {
        const int src = dir ? (SEQ - 1 - tt) : tt;
        sum += cw[d * 4 + k] * xi[src];
      }
    }
    const float v = sum * sigmoidf_(sum);
    xconv[(long)d * NBL + n0 + c] = v;
    tile[p * 8 + rr][c] = f2bf(v);
  }
  __syncthreads();
  #pragma unroll
  for (int p = 0; p < 4; ++p) {
    const int n = n0 + p * 8 + rr;
    dst[(long)n * DINNER + d0 + c] = tile[c][p * 8 + rr];
  }
}

// ---------------- fused x_dbl + delta ----------------
// Stage 1: xdbl = xpw (64,1024) @ xcT (n,1024)^T for a 128-n slice.
//   rows>=32 -> xbc fp32; rows<32 (dt) -> LDS dtS (bf16, n-major).
// Stage 2: delta = softplus(dtw (1024,32) @ dtS^T + dtb), 8 m-tiles of 128.
__global__ __launch_bounds__(256) void xdbl_delta_kernel(
    const unsigned short* __restrict__ xpwb_f, const unsigned short* __restrict__ xpwb_r,
    const unsigned short* __restrict__ xcT,
    const unsigned short* __restrict__ dtwb_f, const unsigned short* __restrict__ dtwb_r,
    const float* __restrict__ dtb_f, const float* __restrict__ dtb_r,
    float* __restrict__ xbc_f, float* __restrict__ xbc_r,
    float* __restrict__ delta_f, float* __restrict__ delta_r) {
  __shared__ unsigned short As[128 * LDK];
  __shared__ unsigned short Bs[128 * LDK];
  __shared__ unsigned short dtS[128 * LDK];
  const int t = threadIdx.x;
  const int dir = blockIdx.y;
  const int n0 = blockIdx.x * 128;
  const unsigned short* A = dir ? xpwb_r : xpwb_f;
  const unsigned short* B = xcT + (long)dir * DINNER * NBL;
  const unsigned short* dtw = dir ? dtwb_r : dtwb_f;
  const float* dtb = dir ? dtb_r : dtb_f;
  float* xbc = dir ? xbc_r : xbc_f;
  float* dl = dir ? delta_r : delta_f;

  const int lane = t & 63;
  const int w = t >> 6;
  const int fr = lane & 15;
  const int fq = lane >> 4;

  // ---- stage 1 ----
  f32x4 acc[4][2];
  #pragma unroll
  for (int i = 0; i < 4; ++i)
    #pragma unroll
    for (int j = 0; j < 2; ++j) {
      f32x4 z = {0.f, 0.f, 0.f, 0.f};
      acc[i][j] = z;
    }
  const int arow = t >> 2, ako = (t & 3) * 8;   // 64 x 32
  const int brow = t >> 1, bko = (t & 1) * 16;  // 128 x 32

  for (int k0 = 0; k0 < DINNER; k0 += 32) {
    if (k0) __syncthreads();
    *(bf16x8*)&As[arow * LDK + ako] =
        *(const bf16x8*)&A[(long)arow * DINNER + k0 + ako];
    *(bf16x8*)&Bs[brow * LDK + bko] =
        *(const bf16x8*)&B[(long)(n0 + brow) * DINNER + k0 + bko];
    *(bf16x8*)&Bs[brow * LDK + bko + 8] =
        *(const bf16x8*)&B[(long)(n0 + brow) * DINNER + k0 + bko + 8];
    __syncthreads();
    bf16x8 af[4], bg[2];
    #pragma unroll
    for (int i = 0; i < 4; ++i)
      af[i] = *(const bf16x8*)&As[(i * 16 + fr) * LDK + fq * 8];
    #pragma unroll
    for (int j = 0; j < 2; ++j)
      bg[j] = *(const bf16x8*)&Bs[(w * 32 + j * 16 + fr) * LDK + fq * 8];
    #pragma unroll
    for (int i = 0; i < 4; ++i)
      #pragma unroll
      for (int j = 0; j < 2; ++j)
        acc[i][j] = __builtin_amdgcn_mfma_f32_16x16x32_bf16(
            af[i], bg[j], acc[i][j], 0, 0, 0);
  }

  #pragma unroll
  for (int i = 0; i < 4; ++i)
    #pragma unroll
    for (int j = 0; j < 2; ++j)
      #pragma unroll
      for (int r2 = 0; r2 < 4; ++r2) {
        const int m = i * 16 + fq * 4 + r2;
        const int nl = w * 32 + j * 16 + fr;
        const float v = acc[i][j][r2];
        if (m < DTRANK) dtS[nl * LDK + m] = f2bf(v);
        else xbc[(long)(n0 + nl) * 32 + (m - 32)] = v;
      }
  __syncthreads();

  // ---- stage 2: delta over 8 m-tiles of 128 d ----
  const int wr = (w >> 1) * 64, wc = (w & 1) * 64;
  const int srow = t >> 1, sko = (t & 1) * 16;
  for (int mt = 0; mt < 8; ++mt) {
    __syncthreads();
    *(bf16x8*)&As[srow * LDK + sko] =
        *(const bf16x8*)&dtw[(long)(mt * 128 + srow) * DTRANK + sko];
    *(bf16x8*)&As[srow * LDK + sko + 8] =
        *(const bf16x8*)&dtw[(long)(mt * 128 + srow) * DTRANK + sko + 8];
    __syncthreads();
    bf16x8 af[4], bg[4];
    #pragma unroll
    for (int i = 0; i < 4; ++i) {
      af[i] = *(const bf16x8*)&As[(wr + i * 16 + fr) * LDK + fq * 8];
      bg[i] = *(const bf16x8*)&dtS[(wc + i * 16 + fr) * LDK + fq * 8];
    }
    #pragma unroll
    for (int i = 0; i < 4; ++i)
      #pragma unroll
      for (int j = 0; j < 4; ++j) {
        f32x4 z = {0.f, 0.f, 0.f, 0.f};
        const f32x4 a2 = __builtin_amdgcn_mfma_f32_16x16x32_bf16(
            af[i], bg[j], z, 0, 0, 0);
        const int mB = mt * 128 + wr + i * 16 + fq * 4;
        const int n = n0 + wc + j * 16 + fr;
        #pragma unroll
        for (int r2 = 0; r2 < 4; ++r2)
          dl[(long)(mB + r2) * NBL + n] = softplusf_(a2[r2] + dtb[mB + r2]);
      }
  }
}

// ---------------- chunked selective scan ----------------
#define NCHK 8
#define CLEN 64
__global__ __launch_bounds__(256) void scan_partA(
    const float* __restrict__ delta_f, const float* __restrict__ delta_r,
    const float* __restrict__ xconv_f, const float* __restrict__ xconv_r,
    const float* __restrict__ xbc_f, const float* __restrict__ xbc_r,
    const float* __restrict__ Alog_f, const float* __restrict__ Alog_r,
    float* __restrict__ hloc, float* __restrict__ aprd) {
  const int t = threadIdx.x;
  const int gid = blockIdx.x * 16 + (t >> 4);
  const int lane = t & 15;
  const int c = gid & (NCHK - 1);
  const int row = gid >> 3;
  const int dir = row >> 11, b = (row >> 10) & 1, d = row & 1023;
  const float* dp = (dir ? delta_r : delta_f) + (long)d * NBL + b * SEQ + c * CLEN;
  const float* up = (dir ? xconv_r : xconv_f) + (long)d * NBL + b * SEQ + c * CLEN;
  const float* bc = (dir ? xbc_r : xbc_f) + ((long)b * SEQ + c * CLEN) * 32;
  const float An = -__expf((dir ? Alog_r : Alog_f)[d * DSTATE + lane]);
  float h = 0.f, P = 1.f;
  #pragma unroll 8
  for (int l = 0; l < CLEN; ++l) {
    const float dt = dp[l], u = up[l];
    const float Bn = bc[l * 32 + lane];
    const float dA = __expf(dt * An);
    h = fmaf(h, dA, dt * u * Bn);
    P *= dA;
  }
  hloc[(long)gid * 16 + lane] = h;
  aprd[(long)gid * 16 + lane] = P;
}

__global__ __launch_bounds__(256) void scan_partB(
    const float* __restrict__ delta_f, const float* __restrict__ delta_r,
    const float* __restrict__ xconv_f, const float* __restrict__ xconv_r,
    const float* __restrict__ xbc_f, const float* __restrict__ xbc_r,
    const float* __restrict__ Alog_f, const float* __restrict__ Alog_r,
    const float* __restrict__ Dsk_f, const float* __restrict__ Dsk_r,
    const float* __restrict__ hloc, const float* __restrict__ aprd,
    const float* __restrict__ xz,
    float* __restrict__ y_f, float* __restrict__ y_r) {
  __shared__ float s_y[16][CLEN + 4];
  const int t = threadIdx.x;
  const int g = t >> 4;
  const int gid = blockIdx.x * 16 + g;
  const int lane = t & 15;
  const int c = gid & (NCHK - 1);
  const int row = gid >> 3;
  const int dir = row >> 11, b = (row >> 10) & 1, d = row & 1023;
  const float* dp = (dir ? delta_r : delta_f) + (long)d * NBL + b * SEQ + c * CLEN;
  const float* up = (dir ? xconv_r : xconv_f) + (long)d * NBL + b * SEQ + c * CLEN;
  const float* bc = (dir ? xbc_r : xbc_f) + ((long)b * SEQ + c * CLEN) * 32;
  const float An = -__expf((dir ? Alog_r : Alog_f)[d * DSTATE + lane]);
  const float Dv = (dir ? Dsk_r : Dsk_f)[d];

  float h = 0.f;
  const long base = (long)(gid & ~(NCHK - 1)) * 16 + lane;
  for (int j = 0; j < c; ++j)
    h = fmaf(h, aprd[base + j * 16], hloc[base + j * 16]);

  #pragma unroll 4
  for (int l = 0; l < CLEN; ++l) {
    const float dt = dp[l], u = up[l];
    const float Bn = bc[l * 32 + lane];
    const float Cn = bc[l * 32 + 16 + lane];
    const float dA = __expf(dt * An);
    h = fmaf(h, dA, dt * u * Bn);
    float pr = h * Cn;
    DPPADD(pr, 0x111);
    DPPADD(pr, 0x112);
    DPPADD(pr, 0x114);
    DPPADD(pr, 0x118);
    if (lane == 0) s_y[g][l] = fmaf(Dv, u, pr);
  }

  const float* zp = xz + (long)(DINNER + d) * NBL + b * SEQ;
  float* yp = (dir ? y_r : y_f) + (long)d * NBL + b * SEQ;
  #pragma unroll
  for (int k = 0; k < 4; ++k) {
    const int l = (lane << 2) + k;
    const int lg = c * CLEN + l;
    const int lo = dir ? (SEQ - 1 - lg) : lg;
    const float z = zp[lo];
    yp[lo] = s_y[g][l] * (z * sigmoidf_(z));
  }
}

// ---------------- out_proj GEMM: 64M x 128N tile, fused y_f+y_r + bf16 ------
// A = out_w bf16 (512 d, 1024 e). B built on the fly from fp32 y_f,y_r (e,n).
// C: hs[n*512 + d] and outp duplicate.
__global__ __launch_bounds__(256) void gemm_out_kernel(
    const unsigned short* __restrict__ A, const float* __restrict__ yf,
    const float* __restrict__ yr, float* __restrict__ C, float* __restrict__ C2) {
  __shared__ unsigned short As[64 * LDK];
  __shared__ unsigned short Bs[128 * LDK];
  const int t = threadIdx.x;
  const int m0 = blockIdx.y * 64, n0 = blockIdx.x * 128;
  const int lane = t & 63;
  const int w = t >> 6;
  const int wr = (w >> 1) * 32, wc = (w & 1) * 64;
  const int fr = lane & 15;
  const int fq = lane >> 4;
  const int K = DINNER;

  f32x4 acc[2][4];
  #pragma unroll
  for (int i = 0; i < 2; ++i)
    #pragma unroll
    for (int j = 0; j < 4; ++j) {
      f32x4 z = {0.f, 0.f, 0.f, 0.f};
      acc[i][j] = z;
    }

  const int arow = t >> 2, ako = (t & 3) * 8;  // A: 64 x 32
  const int kk = t >> 3, nb = (t & 7) * 16;    // B: 32 k x 128 n

  for (int k0 = 0; k0 < K; k0 += 32) {
    if (k0) __syncthreads();
    *(bf16x8*)&As[arow * LDK + ako] =
        *(const bf16x8*)&A[(long)(m0 + arow) * K + k0 + ako];
    #pragma unroll
    for (int q = 0; q < 4; ++q) {
      const int nl = nb + q * 4;
      const float4 fa = *(const float4*)&yf[(long)(k0 + kk) * NBL + n0 + nl];
      const float4 fb = *(const float4*)&yr[(long)(k0 + kk) * NBL + n0 + nl];
      Bs[(nl + 0) * LDK + kk] = f2bf(fa.x + fb.x);
      Bs[(nl + 1) * LDK + kk] = f2bf(fa.y + fb.y);
      Bs[(nl + 2) * LDK + kk] = f2bf(fa.z + fb.z);
      Bs[(nl + 3) * LDK + kk] = f2bf(fa.w + fb.w);
    }
    __syncthreads();
    bf16x8 af[2], bg[4];
    #pragma unroll
    for (int i = 0; i < 2; ++i)
      af[i] = *(const bf16x8*)&As[(wr + i * 16 + fr) * LDK + fq * 8];
    #pragma unroll
    for (int j = 0; j < 4; ++j)
      bg[j] = *(const bf16x8*)&Bs[(wc + j * 16 + fr) * LDK + fq * 8];
    #pragma unroll
    for (int i = 0; i < 2; ++i)
      #pragma unroll
      for (int j = 0; j < 4; ++j)
        acc[i][j] = __builtin_amdgcn_mfma_f32_16x16x32_bf16(
            af[i], bg[j], acc[i][j], 0, 0, 0);
  }

  #pragma unroll
  for (int i = 0; i < 2; ++i)
    #pragma unroll
    for (int j = 0; j < 4; ++j)
      #pragma unroll
      for (int r2 = 0; r2 < 4; ++r2) {
        const int m = m0 + wr + i * 16 + fq * 4 + r2;
        const int n = n0 + wc + j * 16 + fr;
        const long addr = (long)n * DMODEL + m;
        C[addr] = acc[i][j][r2];
        C2[addr] = acc[i][j][r2];
      }
}

extern "C" void kernel_launch(void* const* d_in, const int* in_sizes, int n_in,
                              void* d_out, int out_size, void* d_ws, size_t ws_size,
                              hipStream_t stream) {
  (void)in_sizes; (void)n_in; (void)out_size; (void)ws_size;
  const float* x       = (const float*)d_in[0];
  const float* norm_w  = (const float*)d_in[1];
  const float* in_proj = (const float*)d_in[2];
  const float* convw_f = (const float*)d_in[3];
  const float* convb_f = (const float*)d_in[4];
  const float* xpw_f   = (const float*)d_in[5];
  const float* dtw_f   = (const float*)d_in[6];
  const float* dtb_f   = (const float*)d_in[7];
  const float* Alog_f  = (const float*)d_in[8];
  const float* Dsk_f   = (const float*)d_in[9];
  const float* convw_r = (const float*)d_in[10];
  const float* convb_r = (const float*)d_in[11];
  const float* xpw_r   = (const float*)d_in[12];
  const float* dtw_r   = (const float*)d_in[13];
  const float* dtb_r   = (const float*)d_in[14];
  const float* Alog_r  = (const float*)d_in[15];
  const float* Dsk_r   = (const float*)d_in[16];
  const float* out_w   = (const float*)d_in[17];
  const float* normf_w = (const float*)d_in[18];

  float* ws = (float*)d_ws;
  float* residual = ws;  ws += 524288;
  float* xzbuf    = ws;  ws += 2097152;
  float* xconv_f  = ws;  ws += 1048576;
  float* xconv_r  = ws;  ws += 1048576;
  float* xbc_f    = ws;  ws += 32768;
  float* xbc_r    = ws;  ws += 32768;
  float* delta_f  = ws;  ws += 1048576;
  float* delta_r  = ws;  ws += 1048576;
  float* y_f      = ws;  ws += 1048576;
  float* y_r      = ws;  ws += 1048576;
  float* hs       = ws;  ws += 524288;
  float* hnb_f    = ws;  ws += 262144;   // 1024x512 bf16
  float* wbfin_f  = ws;  ws += 2097152;  // 4x2048x512 bf16
  float* wbfout_f = ws;  ws += 1048576;  // 4x512x1024 bf16
  float* hloc     = ws;  ws += 524288;
  float* aprd     = ws;  ws += 524288;
  float* xcT_f    = ws;  ws += 1048576;  // 2 x 1024 x 1024 bf16
  float* xpwb_f_  = ws;  ws += 131072;   // 4 x 64 x 1024 bf16
  float* xpwb_r_  = ws;  ws += 131072;
  float* dtwb_f_  = ws;  ws += 65536;    // 4 x 1024 x 32 bf16
  float* dtwb_r_  = ws;  ws += 65536;

  unsigned short* hnb = (unsigned short*)hnb_f;
  unsigned short* wbfin = (unsigned short*)wbfin_f;
  unsigned short* wbfout = (unsigned short*)wbfout_f;
  unsigned short* xcT = (unsigned short*)xcT_f;
  unsigned short* xpwb_f = (unsigned short*)xpwb_f_;
  unsigned short* xpwb_r = (unsigned short*)xpwb_r_;
  unsigned short* dtwb_f = (unsigned short*)dtwb_f_;
  unsigned short* dtwb_r = (unsigned short*)dtwb_r_;

  float* outp = (float*)d_out;

  // all weight conversions in one dispatch
  wconvert_kernel<<<3456, 256, 0, stream>>>(
      in_proj, out_w, xpw_f, xpw_r, dtw_f, dtw_r,
      wbfin, wbfout, xpwb_f, xpwb_r, dtwb_f, dtwb_r);

  for (int layer = 0; layer < 4; ++layer) {
    addnorm_kernel<<<1024, 256, 0, stream>>>(
        layer == 0 ? x : hs, residual, norm_w + layer * DMODEL,
        nullptr, hnb, layer == 0 ? 1 : 0);
    gemm_in_kernel<<<dim3(16, 16), 256, 0, stream>>>(
        wbfin + (long)layer * 2048 * 512, hnb, xzbuf);
    conv_silu_kernel<<<dim3(32, 32, 2), 256, 0, stream>>>(
        xzbuf, convw_f + layer * DINNER * 4, convb_f + layer * DINNER,
        convw_r + layer * DINNER * 4, convb_r + layer * DINNER,
        xconv_f, xconv_r, xcT);
    xdbl_delta_kernel<<<dim3(8, 2), 256, 0, stream>>>(
        xpwb_f + (long)layer * 64 * DINNER, xpwb_r + (long)layer * 64 * DINNER,
        xcT, dtwb_f + (long)layer * DINNER * DTRANK,
        dtwb_r + (long)layer * DINNER * DTRANK,
        dtb_f + layer * DINNER, dtb_r + layer * DINNER,
        xbc_f, xbc_r, delta_f, delta_r);
    scan_partA<<<2048, 256, 0, stream>>>(
        delta_f, delta_r, xconv_f, xconv_r, xbc_f, xbc_r,
        Alog_f + layer * DINNER * DSTATE, Alog_r + layer * DINNER * DSTATE,
        hloc, aprd);
    scan_partB<<<2048, 256, 0, stream>>>(
        delta_f, delta_r, xconv_f, xconv_r, xbc_f, xbc_r,
        Alog_f + layer * DINNER * DSTATE, Alog_r + layer * DINNER * DSTATE,
        Dsk_f + layer * DINNER, Dsk_r + layer * DINNER,
        hloc, aprd, xzbuf, y_f, y_r);
    gemm_out_kernel<<<dim3(8, 8), 256, 0, stream>>>(
        wbfout + (long)layer * 512 * 1024, y_f, y_r, hs,
        outp + (long)(1 + layer) * 524288);
  }
  addnorm_kernel<<<1024, 256, 0, stream>>>(hs, residual, normf_w, outp, nullptr, 0);
}

// Round 7
// 602.375 us; speedup vs baseline: 1.7866x; 1.7866x over previous
//
#include <hip/hip_runtime.h>

#define BATCH 2
#define SEQ 512
#define DMODEL 512
#define DINNER 1024
#define DSTATE 16
#define DTRANK 32
#define NBL (BATCH*SEQ)      // 1024
#define EPSV 1e-5f

typedef __attribute__((ext_vector_type(8))) short bf16x8;
typedef __attribute__((ext_vector_type(4))) float f32x4;

static __device__ __forceinline__ float sigmoidf_(float x) {
  return 1.0f / (1.0f + __expf(-x));
}
static __device__ __forceinline__ float softplusf_(float x) {
  return fmaxf(x, 0.0f) + log1pf(__expf(-fabsf(x)));
}
static __device__ __forceinline__ unsigned short f2bf(float x) {
  unsigned int u = __float_as_uint(x);
  unsigned int r = (u + 0x7FFFu + ((u >> 16) & 1u)) >> 16;
  return (unsigned short)r;
}

#define DPPADD(v, ctrl)                                                     \
  v += __int_as_float(__builtin_amdgcn_update_dpp(                          \
      0, __float_as_int(v), ctrl, 0xf, 0xf, true))

// ---------------- all-weight fp32 -> bf16 convert (segmented) ----------------
__global__ __launch_bounds__(256) void wconvert_kernel(
    const float* __restrict__ s0, const float* __restrict__ s1,
    const float* __restrict__ s2, const float* __restrict__ s3,
    const float* __restrict__ s4, const float* __restrict__ s5,
    unsigned short* __restrict__ d0, unsigned short* __restrict__ d1,
    unsigned short* __restrict__ d2, unsigned short* __restrict__ d3,
    unsigned short* __restrict__ d4, unsigned short* __restrict__ d5) {
  long i = (long)(blockIdx.x * 256 + threadIdx.x) * 8;
  const float* src; unsigned short* dst;
  if (i < 4194304)      { src = s0; dst = d0; }
  else if (i < 6291456) { src = s1; dst = d1; i -= 4194304; }
  else if (i < 6553600) { src = s2; dst = d2; i -= 6291456; }
  else if (i < 6815744) { src = s3; dst = d3; i -= 6553600; }
  else if (i < 6946816) { src = s4; dst = d4; i -= 6815744; }
  else                  { src = s5; dst = d5; i -= 6946816; }
  const float4 v0 = *(const float4*)&src[i];
  const float4 v1 = *(const float4*)&src[i + 4];
  bf16x8 o;
  o[0] = (short)f2bf(v0.x); o[1] = (short)f2bf(v0.y);
  o[2] = (short)f2bf(v0.z); o[3] = (short)f2bf(v0.w);
  o[4] = (short)f2bf(v1.x); o[5] = (short)f2bf(v1.y);
  o[6] = (short)f2bf(v1.z); o[7] = (short)f2bf(v1.w);
  *(bf16x8*)&dst[i] = o;
}

// ---------------- fused add + RMSNorm ----------------
__global__ __launch_bounds__(256) void addnorm_kernel(
    const float* __restrict__ hs, float* __restrict__ residual,
    const float* __restrict__ w, float* __restrict__ out,
    unsigned short* __restrict__ outb, int first) {
  const int row = blockIdx.x;
  const int t = threadIdx.x;
  const float* hp = hs + (long)row * DMODEL;
  float* rp = residual + (long)row * DMODEL;
  float r0 = hp[t], r1 = hp[t + 256];
  if (!first) { r0 += rp[t]; r1 += rp[t + 256]; }
  rp[t] = r0; rp[t + 256] = r1;
  float ss = r0 * r0 + r1 * r1;
  #pragma unroll
  for (int off = 32; off; off >>= 1) ss += __shfl_xor(ss, off, 64);
  __shared__ float sw[4];
  const int wid = t >> 6, lane = t & 63;
  if (lane == 0) sw[wid] = ss;
  __syncthreads();
  const float tot = sw[0] + sw[1] + sw[2] + sw[3];
  const float scale = rsqrtf(tot * (1.0f / (float)DMODEL) + EPSV);
  const float v0 = r0 * scale * w[t];
  const float v1 = r1 * scale * w[t + 256];
  if (out) {
    out[(long)row * DMODEL + t] = v0;
    out[(long)row * DMODEL + t + 256] = v1;
  }
  if (outb) {
    outb[(long)row * DMODEL + t] = f2bf(v0);
    outb[(long)row * DMODEL + t + 256] = f2bf(v1);
  }
}

#define LDK 40

// ---------------- in_proj GEMM: 128M x 64N tile, grid (16,16) ----------------
__global__ __launch_bounds__(256) void gemm_in_kernel(
    const unsigned short* __restrict__ A, const unsigned short* __restrict__ B,
    float* __restrict__ C) {
  __shared__ unsigned short As[128 * LDK];
  __shared__ unsigned short Bs[64 * LDK];
  const int t = threadIdx.x;
  const int m0 = blockIdx.y * 128, n0 = blockIdx.x * 64;
  const int lane = t & 63;
  const int w = t >> 6;
  const int wr = (w >> 1) * 64, wc = (w & 1) * 32;
  const int fr = lane & 15;
  const int fq = lane >> 4;
  const int K = DMODEL;

  f32x4 acc[4][2];
  #pragma unroll
  for (int i = 0; i < 4; ++i)
    #pragma unroll
    for (int j = 0; j < 2; ++j) {
      f32x4 z = {0.f, 0.f, 0.f, 0.f};
      acc[i][j] = z;
    }

  const int srow = t >> 1, sko = (t & 1) * 16;   // A: 128 x 32
  const int brow = t >> 2, bko = (t & 3) * 8;    // B: 64 x 32

  for (int k0 = 0; k0 < K; k0 += 32) {
    if (k0) __syncthreads();
    *(bf16x8*)&As[srow * LDK + sko] =
        *(const bf16x8*)&A[(long)(m0 + srow) * K + k0 + sko];
    *(bf16x8*)&As[srow * LDK + sko + 8] =
        *(const bf16x8*)&A[(long)(m0 + srow) * K + k0 + sko + 8];
    *(bf16x8*)&Bs[brow * LDK + bko] =
        *(const bf16x8*)&B[(long)(n0 + brow) * K + k0 + bko];
    __syncthreads();
    bf16x8 af[4], bg[2];
    #pragma unroll
    for (int i = 0; i < 4; ++i)
      af[i] = *(const bf16x8*)&As[(wr + i * 16 + fr) * LDK + fq * 8];
    #pragma unroll
    for (int j = 0; j < 2; ++j)
      bg[j] = *(const bf16x8*)&Bs[(wc + j * 16 + fr) * LDK + fq * 8];
    #pragma unroll
    for (int i = 0; i < 4; ++i)
      #pragma unroll
      for (int j = 0; j < 2; ++j)
        acc[i][j] = __builtin_amdgcn_mfma_f32_16x16x32_bf16(
            af[i], bg[j], acc[i][j], 0, 0, 0);
  }

  #pragma unroll
  for (int i = 0; i < 4; ++i)
    #pragma unroll
    for (int j = 0; j < 2; ++j)
      #pragma unroll
      for (int r2 = 0; r2 < 4; ++r2) {
        const int m = m0 + wr + i * 16 + fq * 4 + r2;
        const int n = n0 + wc + j * 16 + fr;
        C[(long)m * NBL + n] = acc[i][j][r2];
      }
}

// ---------------- conv+SiLU + transposed bf16 out (fused xct) ----------------
__global__ __launch_bounds__(256) void conv_silu_kernel(
    const float* __restrict__ xz,
    const float* __restrict__ cw_f, const float* __restrict__ cb_f,
    const float* __restrict__ cw_r, const float* __restrict__ cb_r,
    float* __restrict__ xconv_f, float* __restrict__ xconv_r,
    unsigned short* __restrict__ xcT) {
  __shared__ unsigned short tile[32][33];
  const int dir = blockIdx.z;
  const int n0 = blockIdx.x * 32, d0 = blockIdx.y * 32;
  const int b = n0 >> 9;
  const int l0 = n0 & (SEQ - 1);
  const float* cw = dir ? cw_r : cw_f;
  const float* cb = dir ? cb_r : cb_f;
  float* xconv = dir ? xconv_r : xconv_f;
  unsigned short* dst = xcT + (long)dir * DINNER * NBL;
  const int t = threadIdx.x;
  const int c = t & 31, rr = t >> 5;
  #pragma unroll
  for (int p = 0; p < 4; ++p) {
    const int d = d0 + p * 8 + rr;
    const int l = l0 + c;
    const float* xi = xz + (long)d * NBL + b * SEQ;
    float sum = cb[d];
    #pragma unroll
    for (int k = 0; k < 4; ++k) {
      const int tt = l - 3 + k;
      if (tt >= 0) {
        const int src = dir ? (SEQ - 1 - tt) : tt;
        sum += cw[d * 4 + k] * xi[src];
      }
    }
    const float v = sum * sigmoidf_(sum);
    xconv[(long)d * NBL + n0 + c] = v;
    tile[p * 8 + rr][c] = f2bf(v);
  }
  __syncthreads();
  #pragma unroll
  for (int p = 0; p < 4; ++p) {
    const int n = n0 + p * 8 + rr;
    dst[(long)n * DINNER + d0 + c] = tile[c][p * 8 + rr];
  }
}

// ---------------- x_dbl via MFMA: (64 x 1024) @ (1024n x 1024K)^T ----------
// rows<32 -> dtT bf16 (dir,n,32); rows>=32 -> xbc fp32 [n*32 + row-32].
__global__ __launch_bounds__(256) void xdbl_mfma_kernel(
    const unsigned short* __restrict__ xpwb_f, const unsigned short* __restrict__ xpwb_r,
    const unsigned short* __restrict__ xcT,
    unsigned short* __restrict__ dtT,
    float* __restrict__ xbc_f, float* __restrict__ xbc_r) {
  __shared__ unsigned short As[64 * LDK];
  __shared__ unsigned short Bs[128 * LDK];
  const int t = threadIdx.x;
  const int dir = blockIdx.y;
  const int n0 = blockIdx.x * 128;
  const unsigned short* A = dir ? xpwb_r : xpwb_f;
  const unsigned short* B = xcT + (long)dir * DINNER * NBL;
  float* xbc = dir ? xbc_r : xbc_f;
  unsigned short* dtt = dtT + (long)dir * NBL * DTRANK;

  const int lane = t & 63;
  const int w = t >> 6;
  const int fr = lane & 15;
  const int fq = lane >> 4;

  f32x4 acc[4][2];
  #pragma unroll
  for (int i = 0; i < 4; ++i)
    #pragma unroll
    for (int j = 0; j < 2; ++j) {
      f32x4 z = {0.f, 0.f, 0.f, 0.f};
      acc[i][j] = z;
    }

  const int arow = t >> 2, ako = (t & 3) * 8;   // 64 rows x 32 k
  const int brow = t >> 1, bko = (t & 1) * 16;  // 128 rows x 32 k

  for (int k0 = 0; k0 < DINNER; k0 += 32) {
    if (k0) __syncthreads();
    *(bf16x8*)&As[arow * LDK + ako] =
        *(const bf16x8*)&A[(long)arow * DINNER + k0 + ako];
    *(bf16x8*)&Bs[brow * LDK + bko] =
        *(const bf16x8*)&B[(long)(n0 + brow) * DINNER + k0 + bko];
    *(bf16x8*)&Bs[brow * LDK + bko + 8] =
        *(const bf16x8*)&B[(long)(n0 + brow) * DINNER + k0 + bko + 8];
    __syncthreads();
    bf16x8 af[4], bg[2];
    #pragma unroll
    for (int i = 0; i < 4; ++i)
      af[i] = *(const bf16x8*)&As[(i * 16 + fr) * LDK + fq * 8];
    #pragma unroll
    for (int j = 0; j < 2; ++j)
      bg[j] = *(const bf16x8*)&Bs[(w * 32 + j * 16 + fr) * LDK + fq * 8];
    #pragma unroll
    for (int i = 0; i < 4; ++i)
      #pragma unroll
      for (int j = 0; j < 2; ++j)
        acc[i][j] = __builtin_amdgcn_mfma_f32_16x16x32_bf16(
            af[i], bg[j], acc[i][j], 0, 0, 0);
  }

  #pragma unroll
  for (int i = 0; i < 4; ++i)
    #pragma unroll
    for (int j = 0; j < 2; ++j)
      #pragma unroll
      for (int r2 = 0; r2 < 4; ++r2) {
        const int m = i * 16 + fq * 4 + r2;
        const int n = n0 + w * 32 + j * 16 + fr;
        const float v = acc[i][j][r2];
        if (m < DTRANK) dtt[(long)n * DTRANK + m] = f2bf(v);
        else xbc[(long)n * 32 + (m - 32)] = v;
      }
}

// ---------------- delta via MFMA: softplus(dtw @ dt + dtb) ----------------
__global__ __launch_bounds__(256) void deltam_kernel(
    const unsigned short* __restrict__ dtwb_f, const unsigned short* __restrict__ dtwb_r,
    const unsigned short* __restrict__ dtT,
    const float* __restrict__ dtb_f, const float* __restrict__ dtb_r,
    float* __restrict__ delta_f, float* __restrict__ delta_r) {
  __shared__ unsigned short As[128 * LDK];
  __shared__ unsigned short Bs[128 * LDK];
  const int t = threadIdx.x;
  const int dir = blockIdx.z;
  const unsigned short* A = dir ? dtwb_r : dtwb_f;
  const unsigned short* B = dtT + (long)dir * NBL * DTRANK;
  const float* dtb = dir ? dtb_r : dtb_f;
  float* dl = dir ? delta_r : delta_f;
  const int m0 = blockIdx.y * 128, n0 = blockIdx.x * 128;
  const int lane = t & 63;
  const int w = t >> 6;
  const int wr = (w >> 1) * 64, wc = (w & 1) * 64;
  const int fr = lane & 15;
  const int fq = lane >> 4;

  const int srow = t >> 1;
  const int sko = (t & 1) * 16;
  *(bf16x8*)&As[srow * LDK + sko] =
      *(const bf16x8*)&A[(long)(m0 + srow) * DTRANK + sko];
  *(bf16x8*)&As[srow * LDK + sko + 8] =
      *(const bf16x8*)&A[(long)(m0 + srow) * DTRANK + sko + 8];
  *(bf16x8*)&Bs[srow * LDK + sko] =
      *(const bf16x8*)&B[(long)(n0 + srow) * DTRANK + sko];
  *(bf16x8*)&Bs[srow * LDK + sko + 8] =
      *(const bf16x8*)&B[(long)(n0 + srow) * DTRANK + sko + 8];
  __syncthreads();

  bf16x8 af[4], bg[4];
  #pragma unroll
  for (int i = 0; i < 4; ++i) {
    af[i] = *(const bf16x8*)&As[(wr + i * 16 + fr) * LDK + fq * 8];
    bg[i] = *(const bf16x8*)&Bs[(wc + i * 16 + fr) * LDK + fq * 8];
  }
  f32x4 acc[4][4];
  #pragma unroll
  for (int i = 0; i < 4; ++i)
    #pragma unroll
    for (int j = 0; j < 4; ++j) {
      f32x4 z = {0.f, 0.f, 0.f, 0.f};
      acc[i][j] = __builtin_amdgcn_mfma_f32_16x16x32_bf16(af[i], bg[j], z, 0, 0, 0);
    }

  #pragma unroll
  for (int i = 0; i < 4; ++i) {
    const int m = m0 + wr + i * 16 + fq * 4;
    #pragma unroll
    for (int r2 = 0; r2 < 4; ++r2) {
      const float bias = dtb[m + r2];
      #pragma unroll
      for (int j = 0; j < 4; ++j) {
        const int n = n0 + wc + j * 16 + fr;
        dl[(long)(m + r2) * NBL + n] = softplusf_(acc[i][j][r2] + bias);
      }
    }
  }
}

// ---------------- chunked selective scan ----------------
#define NCHK 8
#define CLEN 64
__global__ __launch_bounds__(256) void scan_partA(
    const float* __restrict__ delta_f, const float* __restrict__ delta_r,
    const float* __restrict__ xconv_f, const float* __restrict__ xconv_r,
    const float* __restrict__ xbc_f, const float* __restrict__ xbc_r,
    const float* __restrict__ Alog_f, const float* __restrict__ Alog_r,
    float* __restrict__ hloc, float* __restrict__ aprd) {
  const int t = threadIdx.x;
  const int gid = blockIdx.x * 16 + (t >> 4);
  const int lane = t & 15;
  const int c = gid & (NCHK - 1);
  const int row = gid >> 3;
  const int dir = row >> 11, b = (row >> 10) & 1, d = row & 1023;
  const float* dp = (dir ? delta_r : delta_f) + (long)d * NBL + b * SEQ + c * CLEN;
  const float* up = (dir ? xconv_r : xconv_f) + (long)d * NBL + b * SEQ + c * CLEN;
  const float* bc = (dir ? xbc_r : xbc_f) + ((long)b * SEQ + c * CLEN) * 32;
  const float An = -__expf((dir ? Alog_r : Alog_f)[d * DSTATE + lane]);
  float h = 0.f, P = 1.f;
  #pragma unroll 8
  for (int l = 0; l < CLEN; ++l) {
    const float dt = dp[l], u = up[l];
    const float Bn = bc[l * 32 + lane];
    const float dA = __expf(dt * An);
    h = fmaf(h, dA, dt * u * Bn);
    P *= dA;
  }
  hloc[(long)gid * 16 + lane] = h;
  aprd[(long)gid * 16 + lane] = P;
}

__global__ __launch_bounds__(256) void scan_partB(
    const float* __restrict__ delta_f, const float* __restrict__ delta_r,
    const float* __restrict__ xconv_f, const float* __restrict__ xconv_r,
    const float* __restrict__ xbc_f, const float* __restrict__ xbc_r,
    const float* __restrict__ Alog_f, const float* __restrict__ Alog_r,
    const float* __restrict__ Dsk_f, const float* __restrict__ Dsk_r,
    const float* __restrict__ hloc, const float* __restrict__ aprd,
    const float* __restrict__ xz,
    float* __restrict__ y_f, float* __restrict__ y_r) {
  __shared__ float s_y[16][CLEN + 4];
  const int t = threadIdx.x;
  const int g = t >> 4;
  const int gid = blockIdx.x * 16 + g;
  const int lane = t & 15;
  const int c = gid & (NCHK - 1);
  const int row = gid >> 3;
  const int dir = row >> 11, b = (row >> 10) & 1, d = row & 1023;
  const float* dp = (dir ? delta_r : delta_f) + (long)d * NBL + b * SEQ + c * CLEN;
  const float* up = (dir ? xconv_r : xconv_f) + (long)d * NBL + b * SEQ + c * CLEN;
  const float* bc = (dir ? xbc_r : xbc_f) + ((long)b * SEQ + c * CLEN) * 32;
  const float An = -__expf((dir ? Alog_r : Alog_f)[d * DSTATE + lane]);
  const float Dv = (dir ? Dsk_r : Dsk_f)[d];

  float h = 0.f;
  const long base = (long)(gid & ~(NCHK - 1)) * 16 + lane;
  for (int j = 0; j < c; ++j)
    h = fmaf(h, aprd[base + j * 16], hloc[base + j * 16]);

  #pragma unroll 4
  for (int l = 0; l < CLEN; ++l) {
    const float dt = dp[l], u = up[l];
    const float Bn = bc[l * 32 + lane];
    const float Cn = bc[l * 32 + 16 + lane];
    const float dA = __expf(dt * An);
    h = fmaf(h, dA, dt * u * Bn);
    float pr = h * Cn;
    DPPADD(pr, 0x111);
    DPPADD(pr, 0x112);
    DPPADD(pr, 0x114);
    DPPADD(pr, 0x118);
    if (lane == 0) s_y[g][l] = fmaf(Dv, u, pr);
  }

  const float* zp = xz + (long)(DINNER + d) * NBL + b * SEQ;
  float* yp = (dir ? y_r : y_f) + (long)d * NBL + b * SEQ;
  #pragma unroll
  for (int k = 0; k < 4; ++k) {
    const int l = (lane << 2) + k;
    const int lg = c * CLEN + l;
    const int lo = dir ? (SEQ - 1 - lg) : lg;
    const float z = zp[lo];
    yp[lo] = s_y[g][l] * (z * sigmoidf_(z));
  }
}

// ---------------- out_proj GEMM: 64M x 128N tile, fused y_f+y_r + bf16 ------
__global__ __launch_bounds__(256) void gemm_out_kernel(
    const unsigned short* __restrict__ A, const float* __restrict__ yf,
    const float* __restrict__ yr, float* __restrict__ C, float* __restrict__ C2) {
  __shared__ unsigned short As[64 * LDK];
  __shared__ unsigned short Bs[128 * LDK];
  const int t = threadIdx.x;
  const int m0 = blockIdx.y * 64, n0 = blockIdx.x * 128;
  const int lane = t & 63;
  const int w = t >> 6;
  const int wr = (w >> 1) * 32, wc = (w & 1) * 64;
  const int fr = lane & 15;
  const int fq = lane >> 4;
  const int K = DINNER;

  f32x4 acc[2][4];
  #pragma unroll
  for (int i = 0; i < 2; ++i)
    #pragma unroll
    for (int j = 0; j < 4; ++j) {
      f32x4 z = {0.f, 0.f, 0.f, 0.f};
      acc[i][j] = z;
    }

  const int arow = t >> 2, ako = (t & 3) * 8;  // A: 64 x 32
  const int kk = t >> 3, nb = (t & 7) * 16;    // B: 32 k x 128 n

  for (int k0 = 0; k0 < K; k0 += 32) {
    if (k0) __syncthreads();
    *(bf16x8*)&As[arow * LDK + ako] =
        *(const bf16x8*)&A[(long)(m0 + arow) * K + k0 + ako];
    #pragma unroll
    for (int q = 0; q < 4; ++q) {
      const int nl = nb + q * 4;
      const float4 fa = *(const float4*)&yf[(long)(k0 + kk) * NBL + n0 + nl];
      const float4 fb = *(const float4*)&yr[(long)(k0 + kk) * NBL + n0 + nl];
      Bs[(nl + 0) * LDK + kk] = f2bf(fa.x + fb.x);
      Bs[(nl + 1) * LDK + kk] = f2bf(fa.y + fb.y);
      Bs[(nl + 2) * LDK + kk] = f2bf(fa.z + fb.z);
      Bs[(nl + 3) * LDK + kk] = f2bf(fa.w + fb.w);
    }
    __syncthreads();
    bf16x8 af[2], bg[4];
    #pragma unroll
    for (int i = 0; i < 2; ++i)
      af[i] = *(const bf16x8*)&As[(wr + i * 16 + fr) * LDK + fq * 8];
    #pragma unroll
    for (int j = 0; j < 4; ++j)
      bg[j] = *(const bf16x8*)&Bs[(wc + j * 16 + fr) * LDK + fq * 8];
    #pragma unroll
    for (int i = 0; i < 2; ++i)
      #pragma unroll
      for (int j = 0; j < 4; ++j)
        acc[i][j] = __builtin_amdgcn_mfma_f32_16x16x32_bf16(
            af[i], bg[j], acc[i][j], 0, 0, 0);
  }

  #pragma unroll
  for (int i = 0; i < 2; ++i)
    #pragma unroll
    for (int j = 0; j < 4; ++j)
      #pragma unroll
      for (int r2 = 0; r2 < 4; ++r2) {
        const int m = m0 + wr + i * 16 + fq * 4 + r2;
        const int n = n0 + wc + j * 16 + fr;
        const long addr = (long)n * DMODEL + m;
        C[addr] = acc[i][j][r2];
        C2[addr] = acc[i][j][r2];
      }
}

extern "C" void kernel_launch(void* const* d_in, const int* in_sizes, int n_in,
                              void* d_out, int out_size, void* d_ws, size_t ws_size,
                              hipStream_t stream) {
  (void)in_sizes; (void)n_in; (void)out_size; (void)ws_size;
  const float* x       = (const float*)d_in[0];
  const float* norm_w  = (const float*)d_in[1];
  const float* in_proj = (const float*)d_in[2];
  const float* convw_f = (const float*)d_in[3];
  const float* convb_f = (const float*)d_in[4];
  const float* xpw_f   = (const float*)d_in[5];
  const float* dtw_f   = (const float*)d_in[6];
  const float* dtb_f   = (const float*)d_in[7];
  const float* Alog_f  = (const float*)d_in[8];
  const float* Dsk_f   = (const float*)d_in[9];
  const float* convw_r = (const float*)d_in[10];
  const float* convb_r = (const float*)d_in[11];
  const float* xpw_r   = (const float*)d_in[12];
  const float* dtw_r   = (const float*)d_in[13];
  const float* dtb_r   = (const float*)d_in[14];
  const float* Alog_r  = (const float*)d_in[15];
  const float* Dsk_r   = (const float*)d_in[16];
  const float* out_w   = (const float*)d_in[17];
  const float* normf_w = (const float*)d_in[18];

  float* ws = (float*)d_ws;
  float* residual = ws;  ws += 524288;
  float* xzbuf    = ws;  ws += 2097152;
  float* xconv_f  = ws;  ws += 1048576;
  float* xconv_r  = ws;  ws += 1048576;
  float* xbc_f    = ws;  ws += 32768;
  float* xbc_r    = ws;  ws += 32768;
  float* delta_f  = ws;  ws += 1048576;
  float* delta_r  = ws;  ws += 1048576;
  float* y_f      = ws;  ws += 1048576;
  float* y_r      = ws;  ws += 1048576;
  float* hs       = ws;  ws += 524288;
  float* hnb_f    = ws;  ws += 262144;   // 1024x512 bf16
  float* wbfin_f  = ws;  ws += 2097152;  // 4x2048x512 bf16
  float* wbfout_f = ws;  ws += 1048576;  // 4x512x1024 bf16
  float* hloc     = ws;  ws += 524288;
  float* aprd     = ws;  ws += 524288;
  float* xcT_f    = ws;  ws += 1048576;  // 2 x 1024 x 1024 bf16
  float* dtT_f    = ws;  ws += 32768;    // 2 x 1024 x 32 bf16
  float* xpwb_f_  = ws;  ws += 131072;
  float* xpwb_r_  = ws;  ws += 131072;
  float* dtwb_f_  = ws;  ws += 65536;
  float* dtwb_r_  = ws;  ws += 65536;

  unsigned short* hnb = (unsigned short*)hnb_f;
  unsigned short* wbfin = (unsigned short*)wbfin_f;
  unsigned short* wbfout = (unsigned short*)wbfout_f;
  unsigned short* xcT = (unsigned short*)xcT_f;
  unsigned short* dtT = (unsigned short*)dtT_f;
  unsigned short* xpwb_f = (unsigned short*)xpwb_f_;
  unsigned short* xpwb_r = (unsigned short*)xpwb_r_;
  unsigned short* dtwb_f = (unsigned short*)dtwb_f_;
  unsigned short* dtwb_r = (unsigned short*)dtwb_r_;

  float* outp = (float*)d_out;

  wconvert_kernel<<<3456, 256, 0, stream>>>(
      in_proj, out_w, xpw_f, xpw_r, dtw_f, dtw_r,
      wbfin, wbfout, xpwb_f, xpwb_r, dtwb_f, dtwb_r);

  for (int layer = 0; layer < 4; ++layer) {
    addnorm_kernel<<<1024, 256, 0, stream>>>(
        layer == 0 ? x : hs, residual, norm_w + layer * DMODEL,
        nullptr, hnb, layer == 0 ? 1 : 0);
    gemm_in_kernel<<<dim3(16, 16), 256, 0, stream>>>(
        wbfin + (long)layer * 2048 * 512, hnb, xzbuf);
    conv_silu_kernel<<<dim3(32, 32, 2), 256, 0, stream>>>(
        xzbuf, convw_f + layer * DINNER * 4, convb_f + layer * DINNER,
        convw_r + layer * DINNER * 4, convb_r + layer * DINNER,
        xconv_f, xconv_r, xcT);
    xdbl_mfma_kernel<<<dim3(8, 2), 256, 0, stream>>>(
        xpwb_f + (long)layer * 64 * DINNER, xpwb_r + (long)layer * 64 * DINNER,
        xcT, dtT, xbc_f, xbc_r);
    deltam_kernel<<<dim3(8, 8, 2), 256, 0, stream>>>(
        dtwb_f + (long)layer * DINNER * DTRANK, dtwb_r + (long)layer * DINNER * DTRANK,
        dtT, dtb_f + layer * DINNER, dtb_r + layer * DINNER, delta_f, delta_r);
    scan_partA<<<2048, 256, 0, stream>>>(
        delta_f, delta_r, xconv_f, xconv_r, xbc_f, xbc_r,
        Alog_f + layer * DINNER * DSTATE, Alog_r + layer * DINNER * DSTATE,
        hloc, aprd);
    scan_partB<<<2048, 256, 0, stream>>>(
        delta_f, delta_r, xconv_f, xconv_r, xbc_f, xbc_r,
        Alog_f + layer * DINNER * DSTATE, Alog_r + layer * DINNER * DSTATE,
        Dsk_f + layer * DINNER, Dsk_r + layer * DINNER,
        hloc, aprd, xzbuf, y_f, y_r);
    gemm_out_kernel<<<dim3(8, 8), 256, 0, stream>>>(
        wbfout + (long)layer * 512 * 1024, y_f, y_r, hs,
        outp + (long)(1 + layer) * 524288);
  }
  addnorm_kernel<<<1024, 256, 0, stream>>>(hs, residual, normf_w, outp, nullptr, 0);
}

// Round 8
// 526.384 us; speedup vs baseline: 2.0445x; 1.1444x over previous
//
#include <hip/hip_runtime.h>

#define BATCH 2
#define SEQ 512
#define DMODEL 512
#define DINNER 1024
#define DSTATE 16
#define DTRANK 32
#define NBL (BATCH*SEQ)      // 1024
#define EPSV 1e-5f

typedef __attribute__((ext_vector_type(8))) short bf16x8;
typedef __attribute__((ext_vector_type(4))) float f32x4;

static __device__ __forceinline__ float sigmoidf_(float x) {
  return 1.0f / (1.0f + __expf(-x));
}
static __device__ __forceinline__ float softplusf_(float x) {
  return fmaxf(x, 0.0f) + log1pf(__expf(-fabsf(x)));
}
static __device__ __forceinline__ unsigned short f2bf(float x) {
  unsigned int u = __float_as_uint(x);
  unsigned int r = (u + 0x7FFFu + ((u >> 16) & 1u)) >> 16;
  return (unsigned short)r;
}

#define DPPADD(v, ctrl)                                                     \
  v += __int_as_float(__builtin_amdgcn_update_dpp(                          \
      0, __float_as_int(v), ctrl, 0xf, 0xf, true))

// ---------------- all-weight fp32 -> bf16 convert (segmented) ----------------
__global__ __launch_bounds__(256) void wconvert_kernel(
    const float* __restrict__ s0, const float* __restrict__ s1,
    const float* __restrict__ s2, const float* __restrict__ s3,
    const float* __restrict__ s4, const float* __restrict__ s5,
    unsigned short* __restrict__ d0, unsigned short* __restrict__ d1,
    unsigned short* __restrict__ d2, unsigned short* __restrict__ d3,
    unsigned short* __restrict__ d4, unsigned short* __restrict__ d5) {
  long i = (long)(blockIdx.x * 256 + threadIdx.x) * 8;
  const float* src; unsigned short* dst;
  if (i < 4194304)      { src = s0; dst = d0; }
  else if (i < 6291456) { src = s1; dst = d1; i -= 4194304; }
  else if (i < 6553600) { src = s2; dst = d2; i -= 6291456; }
  else if (i < 6815744) { src = s3; dst = d3; i -= 6553600; }
  else if (i < 6946816) { src = s4; dst = d4; i -= 6815744; }
  else                  { src = s5; dst = d5; i -= 6946816; }
  const float4 v0 = *(const float4*)&src[i];
  const float4 v1 = *(const float4*)&src[i + 4];
  bf16x8 o;
  o[0] = (short)f2bf(v0.x); o[1] = (short)f2bf(v0.y);
  o[2] = (short)f2bf(v0.z); o[3] = (short)f2bf(v0.w);
  o[4] = (short)f2bf(v1.x); o[5] = (short)f2bf(v1.y);
  o[6] = (short)f2bf(v1.z); o[7] = (short)f2bf(v1.w);
  *(bf16x8*)&dst[i] = o;
}

// ---------------- fused add + RMSNorm ----------------
__global__ __launch_bounds__(256) void addnorm_kernel(
    const float* __restrict__ hs, float* __restrict__ residual,
    const float* __restrict__ w, float* __restrict__ out,
    unsigned short* __restrict__ outb, int first) {
  const int row = blockIdx.x;
  const int t = threadIdx.x;
  const float* hp = hs + (long)row * DMODEL;
  float* rp = residual + (long)row * DMODEL;
  float r0 = hp[t], r1 = hp[t + 256];
  if (!first) { r0 += rp[t]; r1 += rp[t + 256]; }
  rp[t] = r0; rp[t + 256] = r1;
  float ss = r0 * r0 + r1 * r1;
  #pragma unroll
  for (int off = 32; off; off >>= 1) ss += __shfl_xor(ss, off, 64);
  __shared__ float sw[4];
  const int wid = t >> 6, lane = t & 63;
  if (lane == 0) sw[wid] = ss;
  __syncthreads();
  const float tot = sw[0] + sw[1] + sw[2] + sw[3];
  const float scale = rsqrtf(tot * (1.0f / (float)DMODEL) + EPSV);
  const float v0 = r0 * scale * w[t];
  const float v1 = r1 * scale * w[t + 256];
  if (out) {
    out[(long)row * DMODEL + t] = v0;
    out[(long)row * DMODEL + t + 256] = v1;
  }
  if (outb) {
    outb[(long)row * DMODEL + t] = f2bf(v0);
    outb[(long)row * DMODEL + t + 256] = f2bf(v1);
  }
}

#define LDK 40

// ---------------- in_proj GEMM: 128M x 64N tile, grid (16,16) ----------------
__global__ __launch_bounds__(256) void gemm_in_kernel(
    const unsigned short* __restrict__ A, const unsigned short* __restrict__ B,
    float* __restrict__ C) {
  __shared__ unsigned short As[128 * LDK];
  __shared__ unsigned short Bs[64 * LDK];
  const int t = threadIdx.x;
  const int m0 = blockIdx.y * 128, n0 = blockIdx.x * 64;
  const int lane = t & 63;
  const int w = t >> 6;
  const int wr = (w >> 1) * 64, wc = (w & 1) * 32;
  const int fr = lane & 15;
  const int fq = lane >> 4;
  const int K = DMODEL;

  f32x4 acc[4][2];
  #pragma unroll
  for (int i = 0; i < 4; ++i)
    #pragma unroll
    for (int j = 0; j < 2; ++j) {
      f32x4 z = {0.f, 0.f, 0.f, 0.f};
      acc[i][j] = z;
    }

  const int srow = t >> 1, sko = (t & 1) * 16;   // A: 128 x 32
  const int brow = t >> 2, bko = (t & 3) * 8;    // B: 64 x 32

  for (int k0 = 0; k0 < K; k0 += 32) {
    if (k0) __syncthreads();
    *(bf16x8*)&As[srow * LDK + sko] =
        *(const bf16x8*)&A[(long)(m0 + srow) * K + k0 + sko];
    *(bf16x8*)&As[srow * LDK + sko + 8] =
        *(const bf16x8*)&A[(long)(m0 + srow) * K + k0 + sko + 8];
    *(bf16x8*)&Bs[brow * LDK + bko] =
        *(const bf16x8*)&B[(long)(n0 + brow) * K + k0 + bko];
    __syncthreads();
    bf16x8 af[4], bg[2];
    #pragma unroll
    for (int i = 0; i < 4; ++i)
      af[i] = *(const bf16x8*)&As[(wr + i * 16 + fr) * LDK + fq * 8];
    #pragma unroll
    for (int j = 0; j < 2; ++j)
      bg[j] = *(const bf16x8*)&Bs[(wc + j * 16 + fr) * LDK + fq * 8];
    #pragma unroll
    for (int i = 0; i < 4; ++i)
      #pragma unroll
      for (int j = 0; j < 2; ++j)
        acc[i][j] = __builtin_amdgcn_mfma_f32_16x16x32_bf16(
            af[i], bg[j], acc[i][j], 0, 0, 0);
  }

  #pragma unroll
  for (int i = 0; i < 4; ++i)
    #pragma unroll
    for (int j = 0; j < 2; ++j)
      #pragma unroll
      for (int r2 = 0; r2 < 4; ++r2) {
        const int m = m0 + wr + i * 16 + fq * 4 + r2;
        const int n = n0 + wc + j * 16 + fr;
        C[(long)m * NBL + n] = acc[i][j][r2];
      }
}

// ---------------- conv+SiLU + transposed bf16 out (fused xct) ----------------
__global__ __launch_bounds__(256) void conv_silu_kernel(
    const float* __restrict__ xz,
    const float* __restrict__ cw_f, const float* __restrict__ cb_f,
    const float* __restrict__ cw_r, const float* __restrict__ cb_r,
    float* __restrict__ xconv_f, float* __restrict__ xconv_r,
    unsigned short* __restrict__ xcT) {
  __shared__ unsigned short tile[32][33];
  const int dir = blockIdx.z;
  const int n0 = blockIdx.x * 32, d0 = blockIdx.y * 32;
  const int b = n0 >> 9;
  const int l0 = n0 & (SEQ - 1);
  const float* cw = dir ? cw_r : cw_f;
  const float* cb = dir ? cb_r : cb_f;
  float* xconv = dir ? xconv_r : xconv_f;
  unsigned short* dst = xcT + (long)dir * DINNER * NBL;
  const int t = threadIdx.x;
  const int c = t & 31, rr = t >> 5;
  #pragma unroll
  for (int p = 0; p < 4; ++p) {
    const int d = d0 + p * 8 + rr;
    const int l = l0 + c;
    const float* xi = xz + (long)d * NBL + b * SEQ;
    float sum = cb[d];
    #pragma unroll
    for (int k = 0; k < 4; ++k) {
      const int tt = l - 3 + k;
      if (tt >= 0) {
        const int src = dir ? (SEQ - 1 - tt) : tt;
        sum += cw[d * 4 + k] * xi[src];
      }
    }
    const float v = sum * sigmoidf_(sum);
    xconv[(long)d * NBL + n0 + c] = v;
    tile[p * 8 + rr][c] = f2bf(v);
  }
  __syncthreads();
  #pragma unroll
  for (int p = 0; p < 4; ++p) {
    const int n = n0 + p * 8 + rr;
    dst[(long)n * DINNER + d0 + c] = tile[c][p * 8 + rr];
  }
}

// ---------------- x_dbl via MFMA ----------------
__global__ __launch_bounds__(256) void xdbl_mfma_kernel(
    const unsigned short* __restrict__ xpwb_f, const unsigned short* __restrict__ xpwb_r,
    const unsigned short* __restrict__ xcT,
    unsigned short* __restrict__ dtT,
    float* __restrict__ xbc_f, float* __restrict__ xbc_r) {
  __shared__ unsigned short As[64 * LDK];
  __shared__ unsigned short Bs[128 * LDK];
  const int t = threadIdx.x;
  const int dir = blockIdx.y;
  const int n0 = blockIdx.x * 128;
  const unsigned short* A = dir ? xpwb_r : xpwb_f;
  const unsigned short* B = xcT + (long)dir * DINNER * NBL;
  float* xbc = dir ? xbc_r : xbc_f;
  unsigned short* dtt = dtT + (long)dir * NBL * DTRANK;

  const int lane = t & 63;
  const int w = t >> 6;
  const int fr = lane & 15;
  const int fq = lane >> 4;

  f32x4 acc[4][2];
  #pragma unroll
  for (int i = 0; i < 4; ++i)
    #pragma unroll
    for (int j = 0; j < 2; ++j) {
      f32x4 z = {0.f, 0.f, 0.f, 0.f};
      acc[i][j] = z;
    }

  const int arow = t >> 2, ako = (t & 3) * 8;   // 64 rows x 32 k
  const int brow = t >> 1, bko = (t & 1) * 16;  // 128 rows x 32 k

  for (int k0 = 0; k0 < DINNER; k0 += 32) {
    if (k0) __syncthreads();
    *(bf16x8*)&As[arow * LDK + ako] =
        *(const bf16x8*)&A[(long)arow * DINNER + k0 + ako];
    *(bf16x8*)&Bs[brow * LDK + bko] =
        *(const bf16x8*)&B[(long)(n0 + brow) * DINNER + k0 + bko];
    *(bf16x8*)&Bs[brow * LDK + bko + 8] =
        *(const bf16x8*)&B[(long)(n0 + brow) * DINNER + k0 + bko + 8];
    __syncthreads();
    bf16x8 af[4], bg[2];
    #pragma unroll
    for (int i = 0; i < 4; ++i)
      af[i] = *(const bf16x8*)&As[(i * 16 + fr) * LDK + fq * 8];
    #pragma unroll
    for (int j = 0; j < 2; ++j)
      bg[j] = *(const bf16x8*)&Bs[(w * 32 + j * 16 + fr) * LDK + fq * 8];
    #pragma unroll
    for (int i = 0; i < 4; ++i)
      #pragma unroll
      for (int j = 0; j < 2; ++j)
        acc[i][j] = __builtin_amdgcn_mfma_f32_16x16x32_bf16(
            af[i], bg[j], acc[i][j], 0, 0, 0);
  }

  #pragma unroll
  for (int i = 0; i < 4; ++i)
    #pragma unroll
    for (int j = 0; j < 2; ++j)
      #pragma unroll
      for (int r2 = 0; r2 < 4; ++r2) {
        const int m = i * 16 + fq * 4 + r2;
        const int n = n0 + w * 32 + j * 16 + fr;
        const float v = acc[i][j][r2];
        if (m < DTRANK) dtt[(long)n * DTRANK + m] = f2bf(v);
        else xbc[(long)n * 32 + (m - 32)] = v;
      }
}

// ---------------- delta via MFMA: softplus(dtw @ dt + dtb) ----------------
__global__ __launch_bounds__(256) void deltam_kernel(
    const unsigned short* __restrict__ dtwb_f, const unsigned short* __restrict__ dtwb_r,
    const unsigned short* __restrict__ dtT,
    const float* __restrict__ dtb_f, const float* __restrict__ dtb_r,
    float* __restrict__ delta_f, float* __restrict__ delta_r) {
  __shared__ unsigned short As[128 * LDK];
  __shared__ unsigned short Bs[128 * LDK];
  const int t = threadIdx.x;
  const int dir = blockIdx.z;
  const unsigned short* A = dir ? dtwb_r : dtwb_f;
  const unsigned short* B = dtT + (long)dir * NBL * DTRANK;
  const float* dtb = dir ? dtb_r : dtb_f;
  float* dl = dir ? delta_r : delta_f;
  const int m0 = blockIdx.y * 128, n0 = blockIdx.x * 128;
  const int lane = t & 63;
  const int w = t >> 6;
  const int wr = (w >> 1) * 64, wc = (w & 1) * 64;
  const int fr = lane & 15;
  const int fq = lane >> 4;

  const int srow = t >> 1;
  const int sko = (t & 1) * 16;
  *(bf16x8*)&As[srow * LDK + sko] =
      *(const bf16x8*)&A[(long)(m0 + srow) * DTRANK + sko];
  *(bf16x8*)&As[srow * LDK + sko + 8] =
      *(const bf16x8*)&A[(long)(m0 + srow) * DTRANK + sko + 8];
  *(bf16x8*)&Bs[srow * LDK + sko] =
      *(const bf16x8*)&B[(long)(n0 + srow) * DTRANK + sko];
  *(bf16x8*)&Bs[srow * LDK + sko + 8] =
      *(const bf16x8*)&B[(long)(n0 + srow) * DTRANK + sko + 8];
  __syncthreads();

  bf16x8 af[4], bg[4];
  #pragma unroll
  for (int i = 0; i < 4; ++i) {
    af[i] = *(const bf16x8*)&As[(wr + i * 16 + fr) * LDK + fq * 8];
    bg[i] = *(const bf16x8*)&Bs[(wc + i * 16 + fr) * LDK + fq * 8];
  }
  f32x4 acc[4][4];
  #pragma unroll
  for (int i = 0; i < 4; ++i)
    #pragma unroll
    for (int j = 0; j < 4; ++j) {
      f32x4 z = {0.f, 0.f, 0.f, 0.f};
      acc[i][j] = __builtin_amdgcn_mfma_f32_16x16x32_bf16(af[i], bg[j], z, 0, 0, 0);
    }

  #pragma unroll
  for (int i = 0; i < 4; ++i) {
    const int m = m0 + wr + i * 16 + fq * 4;
    #pragma unroll
    for (int r2 = 0; r2 < 4; ++r2) {
      const float bias = dtb[m + r2];
      #pragma unroll
      for (int j = 0; j < 4; ++j) {
        const int n = n0 + wc + j * 16 + fr;
        dl[(long)(m + r2) * NBL + n] = softplusf_(acc[i][j][r2] + bias);
      }
    }
  }
}

// ---------------- fused chunked selective scan (A+B in one kernel) ----------
// block = 16 groups of 16 lanes = 2 rows x 8 chunks; grid 2048 blocks.
#define NCHK 8
#define CLEN 64
__global__ __launch_bounds__(256) void scan_fused_kernel(
    const float* __restrict__ delta_f, const float* __restrict__ delta_r,
    const float* __restrict__ xconv_f, const float* __restrict__ xconv_r,
    const float* __restrict__ xbc_f, const float* __restrict__ xbc_r,
    const float* __restrict__ Alog_f, const float* __restrict__ Alog_r,
    const float* __restrict__ Dsk_f, const float* __restrict__ Dsk_r,
    const float* __restrict__ xz,
    float* __restrict__ y_f, float* __restrict__ y_r) {
  __shared__ float s_h[16][16];
  __shared__ float s_P[16][16];
  __shared__ float s_y[16][CLEN + 4];

  const int t = threadIdx.x;
  const int g = t >> 4;            // group 0..15
  const int lane = t & 15;         // state index
  const int c = g & 7;             // chunk
  const int row = blockIdx.x * 2 + (g >> 3);
  const int dir = row >> 11, b = (row >> 10) & 1, d = row & 1023;

  const float* dp = (dir ? delta_r : delta_f) + (long)d * NBL + b * SEQ + c * CLEN;
  const float* up = (dir ? xconv_r : xconv_f) + (long)d * NBL + b * SEQ + c * CLEN;
  const float* bc = (dir ? xbc_r : xbc_f) + ((long)b * SEQ + c * CLEN) * 32;
  const float An = -__expf((dir ? Alog_r : Alog_f)[d * DSTATE + lane]);
  const float Dv = (dir ? Dsk_r : Dsk_f)[d];

  // ---- phase A: local scan with h0 = 0 (all chunks) ----
  {
    float h = 0.f, P = 1.f;
    #pragma unroll 8
    for (int l = 0; l < CLEN; ++l) {
      const float dt = dp[l], u = up[l];
      const float Bn = bc[l * 32 + lane];
      const float dA = __expf(dt * An);
      h = fmaf(h, dA, dt * u * Bn);
      P *= dA;
    }
    s_h[g][lane] = h;
    s_P[g][lane] = P;
  }
  __syncthreads();

  // ---- compose true h0 for this chunk: scan of chunks 0..c-1 in order ----
  float h = 0.f;
  const int rbase = g & 8;
  for (int j = 0; j < c; ++j)
    h = fmaf(h, s_P[rbase + j][lane], s_h[rbase + j][lane]);

  // ---- phase B: replay with true h0, reduce y, gated writeback ----
  #pragma unroll 4
  for (int l = 0; l < CLEN; ++l) {
    const float dt = dp[l], u = up[l];
    const float Bn = bc[l * 32 + lane];
    const float Cn = bc[l * 32 + 16 + lane];
    const float dA = __expf(dt * An);
    h = fmaf(h, dA, dt * u * Bn);
    float pr = h * Cn;
    DPPADD(pr, 0x111);
    DPPADD(pr, 0x112);
    DPPADD(pr, 0x114);
    DPPADD(pr, 0x118);
    if (lane == 0) s_y[g][l] = fmaf(Dv, u, pr);
  }

  const float* zp = xz + (long)(DINNER + d) * NBL + b * SEQ;
  float* yp = (dir ? y_r : y_f) + (long)d * NBL + b * SEQ;
  #pragma unroll
  for (int k = 0; k < 4; ++k) {
    const int l = (lane << 2) + k;
    const int lg = c * CLEN + l;
    const int lo = dir ? (SEQ - 1 - lg) : lg;
    const float z = zp[lo];
    yp[lo] = s_y[g][l] * (z * sigmoidf_(z));
  }
}

// ---------------- y transpose + add + bf16: ybt[n][e] = yf[e][n]+yr[e][n] ----
__global__ __launch_bounds__(256) void ytrans_kernel(
    const float* __restrict__ yf, const float* __restrict__ yr,
    unsigned short* __restrict__ yt) {
  __shared__ unsigned short tile[32][33];
  const int e0 = blockIdx.y * 32, n0 = blockIdx.x * 32;
  const int t = threadIdx.x;
  const int c = t & 31, r8 = t >> 5;
  #pragma unroll
  for (int p = 0; p < 4; ++p) {
    const int e = e0 + p * 8 + r8;
    const float v = yf[(long)e * NBL + n0 + c] + yr[(long)e * NBL + n0 + c];
    tile[p * 8 + r8][c] = f2bf(v);
  }
  __syncthreads();
  #pragma unroll
  for (int p = 0; p < 4; ++p) {
    const int n = n0 + p * 8 + r8;
    yt[(long)n * DINNER + e0 + c] = tile[c][p * 8 + r8];
  }
}

// ---------------- out_proj GEMM, 128x128 tile (round-5 proven path) ---------
__global__ __launch_bounds__(256) void gemm_out_kernel(
    const unsigned short* __restrict__ A, const unsigned short* __restrict__ B,
    float* __restrict__ C, float* __restrict__ C2) {
  __shared__ unsigned short As[128 * LDK];
  __shared__ unsigned short Bs[128 * LDK];
  const int t = threadIdx.x;
  const int m0 = blockIdx.y * 128, n0 = blockIdx.x * 128;
  const int lane = t & 63;
  const int w = t >> 6;
  const int wr = (w >> 1) * 64, wc = (w & 1) * 64;
  const int fr = lane & 15;
  const int fq = lane >> 4;
  const int K = DINNER;

  f32x4 acc[4][4];
  #pragma unroll
  for (int i = 0; i < 4; ++i)
    #pragma unroll
    for (int j = 0; j < 4; ++j) {
      f32x4 z = {0.f, 0.f, 0.f, 0.f};
      acc[i][j] = z;
    }

  const int srow = t >> 1;
  const int sko = (t & 1) * 16;

  for (int k0 = 0; k0 < K; k0 += 32) {
    if (k0) __syncthreads();
    *(bf16x8*)&As[srow * LDK + sko] =
        *(const bf16x8*)&A[(long)(m0 + srow) * K + k0 + sko];
    *(bf16x8*)&As[srow * LDK + sko + 8] =
        *(const bf16x8*)&A[(long)(m0 + srow) * K + k0 + sko + 8];
    *(bf16x8*)&Bs[srow * LDK + sko] =
        *(const bf16x8*)&B[(long)(n0 + srow) * K + k0 + sko];
    *(bf16x8*)&Bs[srow * LDK + sko + 8] =
        *(const bf16x8*)&B[(long)(n0 + srow) * K + k0 + sko + 8];
    __syncthreads();
    bf16x8 af[4], bg[4];
    #pragma unroll
    for (int i = 0; i < 4; ++i) {
      af[i] = *(const bf16x8*)&As[(wr + i * 16 + fr) * LDK + fq * 8];
      bg[i] = *(const bf16x8*)&Bs[(wc + i * 16 + fr) * LDK + fq * 8];
    }
    #pragma unroll
    for (int i = 0; i < 4; ++i)
      #pragma unroll
      for (int j = 0; j < 4; ++j)
        acc[i][j] = __builtin_amdgcn_mfma_f32_16x16x32_bf16(
            af[i], bg[j], acc[i][j], 0, 0, 0);
  }

  #pragma unroll
  for (int i = 0; i < 4; ++i)
    #pragma unroll
    for (int j = 0; j < 4; ++j)
      #pragma unroll
      for (int r2 = 0; r2 < 4; ++r2) {
        const int m = m0 + wr + i * 16 + fq * 4 + r2;
        const int n = n0 + wc + j * 16 + fr;
        const long addr = (long)n * DMODEL + m;
        C[addr] = acc[i][j][r2];
        C2[addr] = acc[i][j][r2];
      }
}

extern "C" void kernel_launch(void* const* d_in, const int* in_sizes, int n_in,
                              void* d_out, int out_size, void* d_ws, size_t ws_size,
                              hipStream_t stream) {
  (void)in_sizes; (void)n_in; (void)out_size; (void)ws_size;
  const float* x       = (const float*)d_in[0];
  const float* norm_w  = (const float*)d_in[1];
  const float* in_proj = (const float*)d_in[2];
  const float* convw_f = (const float*)d_in[3];
  const float* convb_f = (const float*)d_in[4];
  const float* xpw_f   = (const float*)d_in[5];
  const float* dtw_f   = (const float*)d_in[6];
  const float* dtb_f   = (const float*)d_in[7];
  const float* Alog_f  = (const float*)d_in[8];
  const float* Dsk_f   = (const float*)d_in[9];
  const float* convw_r = (const float*)d_in[10];
  const float* convb_r = (const float*)d_in[11];
  const float* xpw_r   = (const float*)d_in[12];
  const float* dtw_r   = (const float*)d_in[13];
  const float* dtb_r   = (const float*)d_in[14];
  const float* Alog_r  = (const float*)d_in[15];
  const float* Dsk_r   = (const float*)d_in[16];
  const float* out_w   = (const float*)d_in[17];
  const float* normf_w = (const float*)d_in[18];

  float* ws = (float*)d_ws;
  float* residual = ws;  ws += 524288;
  float* xzbuf    = ws;  ws += 2097152;
  float* xconv_f  = ws;  ws += 1048576;
  float* xconv_r  = ws;  ws += 1048576;
  float* xbc_f    = ws;  ws += 32768;
  float* xbc_r    = ws;  ws += 32768;
  float* delta_f  = ws;  ws += 1048576;
  float* delta_r  = ws;  ws += 1048576;
  float* y_f      = ws;  ws += 1048576;
  float* y_r      = ws;  ws += 1048576;
  float* hs       = ws;  ws += 524288;
  float* hnb_f    = ws;  ws += 262144;   // 1024x512 bf16
  float* wbfin_f  = ws;  ws += 2097152;  // 4x2048x512 bf16
  float* wbfout_f = ws;  ws += 1048576;  // 4x512x1024 bf16
  float* ybt_f    = ws;  ws += 524288;   // 1024x1024 bf16
  float* xcT_f    = ws;  ws += 1048576;  // 2 x 1024 x 1024 bf16
  float* dtT_f    = ws;  ws += 32768;    // 2 x 1024 x 32 bf16
  float* xpwb_f_  = ws;  ws += 131072;
  float* xpwb_r_  = ws;  ws += 131072;
  float* dtwb_f_  = ws;  ws += 65536;
  float* dtwb_r_  = ws;  ws += 65536;

  unsigned short* hnb = (unsigned short*)hnb_f;
  unsigned short* wbfin = (unsigned short*)wbfin_f;
  unsigned short* wbfout = (unsigned short*)wbfout_f;
  unsigned short* ybt = (unsigned short*)ybt_f;
  unsigned short* xcT = (unsigned short*)xcT_f;
  unsigned short* dtT = (unsigned short*)dtT_f;
  unsigned short* xpwb_f = (unsigned short*)xpwb_f_;
  unsigned short* xpwb_r = (unsigned short*)xpwb_r_;
  unsigned short* dtwb_f = (unsigned short*)dtwb_f_;
  unsigned short* dtwb_r = (unsigned short*)dtwb_r_;

  float* outp = (float*)d_out;

  wconvert_kernel<<<3456, 256, 0, stream>>>(
      in_proj, out_w, xpw_f, xpw_r, dtw_f, dtw_r,
      wbfin, wbfout, xpwb_f, xpwb_r, dtwb_f, dtwb_r);

  for (int layer = 0; layer < 4; ++layer) {
    addnorm_kernel<<<1024, 256, 0, stream>>>(
        layer == 0 ? x : hs, residual, norm_w + layer * DMODEL,
        nullptr, hnb, layer == 0 ? 1 : 0);
    gemm_in_kernel<<<dim3(16, 16), 256, 0, stream>>>(
        wbfin + (long)layer * 2048 * 512, hnb, xzbuf);
    conv_silu_kernel<<<dim3(32, 32, 2), 256, 0, stream>>>(
        xzbuf, convw_f + layer * DINNER * 4, convb_f + layer * DINNER,
        convw_r + layer * DINNER * 4, convb_r + layer * DINNER,
        xconv_f, xconv_r, xcT);
    xdbl_mfma_kernel<<<dim3(8, 2), 256, 0, stream>>>(
        xpwb_f + (long)layer * 64 * DINNER, xpwb_r + (long)layer * 64 * DINNER,
        xcT, dtT, xbc_f, xbc_r);
    deltam_kernel<<<dim3(8, 8, 2), 256, 0, stream>>>(
        dtwb_f + (long)layer * DINNER * DTRANK, dtwb_r + (long)layer * DINNER * DTRANK,
        dtT, dtb_f + layer * DINNER, dtb_r + layer * DINNER, delta_f, delta_r);
    scan_fused_kernel<<<2048, 256, 0, stream>>>(
        delta_f, delta_r, xconv_f, xconv_r, xbc_f, xbc_r,
        Alog_f + layer * DINNER * DSTATE, Alog_r + layer * DINNER * DSTATE,
        Dsk_f + layer * DINNER, Dsk_r + layer * DINNER,
        xzbuf, y_f, y_r);
    ytrans_kernel<<<dim3(32, 32), 256, 0, stream>>>(y_f, y_r, ybt);
    gemm_out_kernel<<<dim3(8, 4), 256, 0, stream>>>(
        wbfout + (long)layer * 512 * 1024, ybt, hs,
        outp + (long)(1 + layer) * 524288);
  }
  addnorm_kernel<<<1024, 256, 0, stream>>>(hs, residual, normf_w, outp, nullptr, 0);
}

// Round 9
// 457.051 us; speedup vs baseline: 2.3547x; 1.1517x over previous
//
#include <hip/hip_runtime.h>

#define BATCH 2
#define SEQ 512
#define DMODEL 512
#define DINNER 1024
#define DSTATE 16
#define DTRANK 32
#define NBL (BATCH*SEQ)      // 1024
#define EPSV 1e-5f

typedef __attribute__((ext_vector_type(8))) short bf16x8;
typedef __attribute__((ext_vector_type(4))) float f32x4;

static __device__ __forceinline__ float sigmoidf_(float x) {
  return 1.0f / (1.0f + __expf(-x));
}
static __device__ __forceinline__ float softplusf_(float x) {
  return fmaxf(x, 0.0f) + log1pf(__expf(-fabsf(x)));
}
static __device__ __forceinline__ unsigned short f2bf(float x) {
  unsigned int u = __float_as_uint(x);
  unsigned int r = (u + 0x7FFFu + ((u >> 16) & 1u)) >> 16;
  return (unsigned short)r;
}

// ---------------- all-weight fp32 -> bf16 convert (segmented) ----------------
__global__ __launch_bounds__(256) void wconvert_kernel(
    const float* __restrict__ s0, const float* __restrict__ s1,
    const float* __restrict__ s2, const float* __restrict__ s3,
    const float* __restrict__ s4, const float* __restrict__ s5,
    unsigned short* __restrict__ d0, unsigned short* __restrict__ d1,
    unsigned short* __restrict__ d2, unsigned short* __restrict__ d3,
    unsigned short* __restrict__ d4, unsigned short* __restrict__ d5) {
  long i = (long)(blockIdx.x * 256 + threadIdx.x) * 8;
  const float* src; unsigned short* dst;
  if (i < 4194304)      { src = s0; dst = d0; }
  else if (i < 6291456) { src = s1; dst = d1; i -= 4194304; }
  else if (i < 6553600) { src = s2; dst = d2; i -= 6291456; }
  else if (i < 6815744) { src = s3; dst = d3; i -= 6553600; }
  else if (i < 6946816) { src = s4; dst = d4; i -= 6815744; }
  else                  { src = s5; dst = d5; i -= 6946816; }
  const float4 v0 = *(const float4*)&src[i];
  const float4 v1 = *(const float4*)&src[i + 4];
  bf16x8 o;
  o[0] = (short)f2bf(v0.x); o[1] = (short)f2bf(v0.y);
  o[2] = (short)f2bf(v0.z); o[3] = (short)f2bf(v0.w);
  o[4] = (short)f2bf(v1.x); o[5] = (short)f2bf(v1.y);
  o[6] = (short)f2bf(v1.z); o[7] = (short)f2bf(v1.w);
  *(bf16x8*)&dst[i] = o;
}

// ---------------- fused add + RMSNorm ----------------
__global__ __launch_bounds__(256) void addnorm_kernel(
    const float* __restrict__ hs, float* __restrict__ residual,
    const float* __restrict__ w, float* __restrict__ out,
    unsigned short* __restrict__ outb, int first) {
  const int row = blockIdx.x;
  const int t = threadIdx.x;
  const float* hp = hs + (long)row * DMODEL;
  float* rp = residual + (long)row * DMODEL;
  float r0 = hp[t], r1 = hp[t + 256];
  if (!first) { r0 += rp[t]; r1 += rp[t + 256]; }
  rp[t] = r0; rp[t + 256] = r1;
  float ss = r0 * r0 + r1 * r1;
  #pragma unroll
  for (int off = 32; off; off >>= 1) ss += __shfl_xor(ss, off, 64);
  __shared__ float sw[4];
  const int wid = t >> 6, lane = t & 63;
  if (lane == 0) sw[wid] = ss;
  __syncthreads();
  const float tot = sw[0] + sw[1] + sw[2] + sw[3];
  const float scale = rsqrtf(tot * (1.0f / (float)DMODEL) + EPSV);
  const float v0 = r0 * scale * w[t];
  const float v1 = r1 * scale * w[t + 256];
  if (out) {
    out[(long)row * DMODEL + t] = v0;
    out[(long)row * DMODEL + t + 256] = v1;
  }
  if (outb) {
    outb[(long)row * DMODEL + t] = f2bf(v0);
    outb[(long)row * DMODEL + t + 256] = f2bf(v1);
  }
}

#define LDK 40

// ---------------- in_proj GEMM: 128M x 64N tile, grid (16,16) ----------------
__global__ __launch_bounds__(256) void gemm_in_kernel(
    const unsigned short* __restrict__ A, const unsigned short* __restrict__ B,
    float* __restrict__ C) {
  __shared__ unsigned short As[128 * LDK];
  __shared__ unsigned short Bs[64 * LDK];
  const int t = threadIdx.x;
  const int m0 = blockIdx.y * 128, n0 = blockIdx.x * 64;
  const int lane = t & 63;
  const int w = t >> 6;
  const int wr = (w >> 1) * 64, wc = (w & 1) * 32;
  const int fr = lane & 15;
  const int fq = lane >> 4;
  const int K = DMODEL;

  f32x4 acc[4][2];
  #pragma unroll
  for (int i = 0; i < 4; ++i)
    #pragma unroll
    for (int j = 0; j < 2; ++j) {
      f32x4 z = {0.f, 0.f, 0.f, 0.f};
      acc[i][j] = z;
    }

  const int srow = t >> 1, sko = (t & 1) * 16;   // A: 128 x 32
  const int brow = t >> 2, bko = (t & 3) * 8;    // B: 64 x 32

  for (int k0 = 0; k0 < K; k0 += 32) {
    if (k0) __syncthreads();
    *(bf16x8*)&As[srow * LDK + sko] =
        *(const bf16x8*)&A[(long)(m0 + srow) * K + k0 + sko];
    *(bf16x8*)&As[srow * LDK + sko + 8] =
        *(const bf16x8*)&A[(long)(m0 + srow) * K + k0 + sko + 8];
    *(bf16x8*)&Bs[brow * LDK + bko] =
        *(const bf16x8*)&B[(long)(n0 + brow) * K + k0 + bko];
    __syncthreads();
    bf16x8 af[4], bg[2];
    #pragma unroll
    for (int i = 0; i < 4; ++i)
      af[i] = *(const bf16x8*)&As[(wr + i * 16 + fr) * LDK + fq * 8];
    #pragma unroll
    for (int j = 0; j < 2; ++j)
      bg[j] = *(const bf16x8*)&Bs[(wc + j * 16 + fr) * LDK + fq * 8];
    #pragma unroll
    for (int i = 0; i < 4; ++i)
      #pragma unroll
      for (int j = 0; j < 2; ++j)
        acc[i][j] = __builtin_amdgcn_mfma_f32_16x16x32_bf16(
            af[i], bg[j], acc[i][j], 0, 0, 0);
  }

  #pragma unroll
  for (int i = 0; i < 4; ++i)
    #pragma unroll
    for (int j = 0; j < 2; ++j)
      #pragma unroll
      for (int r2 = 0; r2 < 4; ++r2) {
        const int m = m0 + wr + i * 16 + fq * 4 + r2;
        const int n = n0 + wc + j * 16 + fr;
        C[(long)m * NBL + n] = acc[i][j][r2];
      }
}

// ---------------- conv+SiLU + transposed bf16 out (fused xct) ----------------
__global__ __launch_bounds__(256) void conv_silu_kernel(
    const float* __restrict__ xz,
    const float* __restrict__ cw_f, const float* __restrict__ cb_f,
    const float* __restrict__ cw_r, const float* __restrict__ cb_r,
    float* __restrict__ xconv_f, float* __restrict__ xconv_r,
    unsigned short* __restrict__ xcT) {
  __shared__ unsigned short tile[32][33];
  const int dir = blockIdx.z;
  const int n0 = blockIdx.x * 32, d0 = blockIdx.y * 32;
  const int b = n0 >> 9;
  const int l0 = n0 & (SEQ - 1);
  const float* cw = dir ? cw_r : cw_f;
  const float* cb = dir ? cb_r : cb_f;
  float* xconv = dir ? xconv_r : xconv_f;
  unsigned short* dst = xcT + (long)dir * DINNER * NBL;
  const int t = threadIdx.x;
  const int c = t & 31, rr = t >> 5;
  #pragma unroll
  for (int p = 0; p < 4; ++p) {
    const int d = d0 + p * 8 + rr;
    const int l = l0 + c;
    const float* xi = xz + (long)d * NBL + b * SEQ;
    float sum = cb[d];
    #pragma unroll
    for (int k = 0; k < 4; ++k) {
      const int tt = l - 3 + k;
      if (tt >= 0) {
        const int src = dir ? (SEQ - 1 - tt) : tt;
        sum += cw[d * 4 + k] * xi[src];
      }
    }
    const float v = sum * sigmoidf_(sum);
    xconv[(long)d * NBL + n0 + c] = v;
    tile[p * 8 + rr][c] = f2bf(v);
  }
  __syncthreads();
  #pragma unroll
  for (int p = 0; p < 4; ++p) {
    const int n = n0 + p * 8 + rr;
    dst[(long)n * DINNER + d0 + c] = tile[c][p * 8 + rr];
  }
}

// ---------------- x_dbl via MFMA ----------------
// rows<32 -> dtT bf16 (dir,n,32); rows>=32 -> xbcT fp32 [slot][NBL] slot-major.
__global__ __launch_bounds__(256) void xdbl_mfma_kernel(
    const unsigned short* __restrict__ xpwb_f, const unsigned short* __restrict__ xpwb_r,
    const unsigned short* __restrict__ xcT,
    unsigned short* __restrict__ dtT,
    float* __restrict__ xbc_f, float* __restrict__ xbc_r) {
  __shared__ unsigned short As[64 * LDK];
  __shared__ unsigned short Bs[128 * LDK];
  const int t = threadIdx.x;
  const int dir = blockIdx.y;
  const int n0 = blockIdx.x * 128;
  const unsigned short* A = dir ? xpwb_r : xpwb_f;
  const unsigned short* B = xcT + (long)dir * DINNER * NBL;
  float* xbc = dir ? xbc_r : xbc_f;
  unsigned short* dtt = dtT + (long)dir * NBL * DTRANK;

  const int lane = t & 63;
  const int w = t >> 6;
  const int fr = lane & 15;
  const int fq = lane >> 4;

  f32x4 acc[4][2];
  #pragma unroll
  for (int i = 0; i < 4; ++i)
    #pragma unroll
    for (int j = 0; j < 2; ++j) {
      f32x4 z = {0.f, 0.f, 0.f, 0.f};
      acc[i][j] = z;
    }

  const int arow = t >> 2, ako = (t & 3) * 8;   // 64 rows x 32 k
  const int brow = t >> 1, bko = (t & 1) * 16;  // 128 rows x 32 k

  for (int k0 = 0; k0 < DINNER; k0 += 32) {
    if (k0) __syncthreads();
    *(bf16x8*)&As[arow * LDK + ako] =
        *(const bf16x8*)&A[(long)arow * DINNER + k0 + ako];
    *(bf16x8*)&Bs[brow * LDK + bko] =
        *(const bf16x8*)&B[(long)(n0 + brow) * DINNER + k0 + bko];
    *(bf16x8*)&Bs[brow * LDK + bko + 8] =
        *(const bf16x8*)&B[(long)(n0 + brow) * DINNER + k0 + bko + 8];
    __syncthreads();
    bf16x8 af[4], bg[2];
    #pragma unroll
    for (int i = 0; i < 4; ++i)
      af[i] = *(const bf16x8*)&As[(i * 16 + fr) * LDK + fq * 8];
    #pragma unroll
    for (int j = 0; j < 2; ++j)
      bg[j] = *(const bf16x8*)&Bs[(w * 32 + j * 16 + fr) * LDK + fq * 8];
    #pragma unroll
    for (int i = 0; i < 4; ++i)
      #pragma unroll
      for (int j = 0; j < 2; ++j)
        acc[i][j] = __builtin_amdgcn_mfma_f32_16x16x32_bf16(
            af[i], bg[j], acc[i][j], 0, 0, 0);
  }

  #pragma unroll
  for (int i = 0; i < 4; ++i)
    #pragma unroll
    for (int j = 0; j < 2; ++j)
      #pragma unroll
      for (int r2 = 0; r2 < 4; ++r2) {
        const int m = i * 16 + fq * 4 + r2;
        const int n = n0 + w * 32 + j * 16 + fr;
        const float v = acc[i][j][r2];
        if (m < DTRANK) dtt[(long)n * DTRANK + m] = f2bf(v);
        else xbc[(long)(m - 32) * NBL + n] = v;   // slot-major
      }
}

// ---------------- delta via MFMA: softplus(dtw @ dt + dtb) ----------------
__global__ __launch_bounds__(256) void deltam_kernel(
    const unsigned short* __restrict__ dtwb_f, const unsigned short* __restrict__ dtwb_r,
    const unsigned short* __restrict__ dtT,
    const float* __restrict__ dtb_f, const float* __restrict__ dtb_r,
    float* __restrict__ delta_f, float* __restrict__ delta_r) {
  __shared__ unsigned short As[128 * LDK];
  __shared__ unsigned short Bs[128 * LDK];
  const int t = threadIdx.x;
  const int dir = blockIdx.z;
  const unsigned short* A = dir ? dtwb_r : dtwb_f;
  const unsigned short* B = dtT + (long)dir * NBL * DTRANK;
  const float* dtb = dir ? dtb_r : dtb_f;
  float* dl = dir ? delta_r : delta_f;
  const int m0 = blockIdx.y * 128, n0 = blockIdx.x * 128;
  const int lane = t & 63;
  const int w = t >> 6;
  const int wr = (w >> 1) * 64, wc = (w & 1) * 64;
  const int fr = lane & 15;
  const int fq = lane >> 4;

  const int srow = t >> 1;
  const int sko = (t & 1) * 16;
  *(bf16x8*)&As[srow * LDK + sko] =
      *(const bf16x8*)&A[(long)(m0 + srow) * DTRANK + sko];
  *(bf16x8*)&As[srow * LDK + sko + 8] =
      *(const bf16x8*)&A[(long)(m0 + srow) * DTRANK + sko + 8];
  *(bf16x8*)&Bs[srow * LDK + sko] =
      *(const bf16x8*)&B[(long)(n0 + srow) * DTRANK + sko];
  *(bf16x8*)&Bs[srow * LDK + sko + 8] =
      *(const bf16x8*)&B[(long)(n0 + srow) * DTRANK + sko + 8];
  __syncthreads();

  bf16x8 af[4], bg[4];
  #pragma unroll
  for (int i = 0; i < 4; ++i) {
    af[i] = *(const bf16x8*)&As[(wr + i * 16 + fr) * LDK + fq * 8];
    bg[i] = *(const bf16x8*)&Bs[(wc + i * 16 + fr) * LDK + fq * 8];
  }
  f32x4 acc[4][4];
  #pragma unroll
  for (int i = 0; i < 4; ++i)
    #pragma unroll
    for (int j = 0; j < 4; ++j) {
      f32x4 z = {0.f, 0.f, 0.f, 0.f};
      acc[i][j] = __builtin_amdgcn_mfma_f32_16x16x32_bf16(af[i], bg[j], z, 0, 0, 0);
    }

  #pragma unroll
  for (int i = 0; i < 4; ++i) {
    const int m = m0 + wr + i * 16 + fq * 4;
    #pragma unroll
    for (int r2 = 0; r2 < 4; ++r2) {
      const float bias = dtb[m + r2];
      #pragma unroll
      for (int j = 0; j < 4; ++j) {
        const int n = n0 + wc + j * 16 + fr;
        dl[(long)(m + r2) * NBL + n] = softplusf_(acc[i][j][r2] + bias);
      }
    }
  }
}

// ---------------- selective scan: one wave per row, lane owns 8 steps -------
// Per state n: 8-step local recurrence (cache dA, c in regs), 6-step shfl_up
// wave-scan composes h0 across lanes, 8-step replay accumulates y in regs.
// No LDS, no barriers, exp once per (l,n). xbcT is slot-major [32][NBL].
__global__ __launch_bounds__(256) void scan_wave_kernel(
    const float* __restrict__ delta_f, const float* __restrict__ delta_r,
    const float* __restrict__ xconv_f, const float* __restrict__ xconv_r,
    const float* __restrict__ xbc_f, const float* __restrict__ xbc_r,
    const float* __restrict__ Alog_f, const float* __restrict__ Alog_r,
    const float* __restrict__ Dsk_f, const float* __restrict__ Dsk_r,
    const float* __restrict__ xz,
    float* __restrict__ y_f, float* __restrict__ y_r) {
  const int t = threadIdx.x;
  const int wv = t >> 6;
  const int lane = t & 63;
  const int row = blockIdx.x * 4 + wv;          // 0..4095
  const int dir = row >> 11, b = (row >> 10) & 1, d = row & 1023;

  const long rbase = (long)d * NBL + b * SEQ;
  const float* dp = (dir ? delta_r : delta_f) + rbase + lane * 8;
  const float* up = (dir ? xconv_r : xconv_f) + rbase + lane * 8;
  const float* bct = (dir ? xbc_r : xbc_f) + b * SEQ + lane * 8;
  const float* Alog = (dir ? Alog_r : Alog_f) + d * DSTATE;
  const float Dv = (dir ? Dsk_r : Dsk_f)[d];

  float dt[8], u[8], dtu[8], y[8];
  {
    const float4 a0 = *(const float4*)&dp[0];
    const float4 a1 = *(const float4*)&dp[4];
    dt[0] = a0.x; dt[1] = a0.y; dt[2] = a0.z; dt[3] = a0.w;
    dt[4] = a1.x; dt[5] = a1.y; dt[6] = a1.z; dt[7] = a1.w;
    const float4 b0 = *(const float4*)&up[0];
    const float4 b1 = *(const float4*)&up[4];
    u[0] = b0.x; u[1] = b0.y; u[2] = b0.z; u[3] = b0.w;
    u[4] = b1.x; u[5] = b1.y; u[6] = b1.z; u[7] = b1.w;
  }
  #pragma unroll
  for (int j = 0; j < 8; ++j) { dtu[j] = dt[j] * u[j]; y[j] = 0.f; }

  for (int n = 0; n < DSTATE; ++n) {
    const float An = -__expf(Alog[n]);
    float Bv[8], Cv[8], dA[8], cB[8];
    {
      const float* bp = bct + (long)n * NBL;
      const float* cp = bct + (long)(DSTATE + n) * NBL;
      const float4 b0 = *(const float4*)&bp[0];
      const float4 b1 = *(const float4*)&bp[4];
      Bv[0] = b0.x; Bv[1] = b0.y; Bv[2] = b0.z; Bv[3] = b0.w;
      Bv[4] = b1.x; Bv[5] = b1.y; Bv[6] = b1.z; Bv[7] = b1.w;
      const float4 c0 = *(const float4*)&cp[0];
      const float4 c1 = *(const float4*)&cp[4];
      Cv[0] = c0.x; Cv[1] = c0.y; Cv[2] = c0.z; Cv[3] = c0.w;
      Cv[4] = c1.x; Cv[5] = c1.y; Cv[6] = c1.z; Cv[7] = c1.w;
    }
    // local scan over this lane's 8 steps (h0 = 0)
    float h = 0.f, P = 1.f;
    #pragma unroll
    for (int j = 0; j < 8; ++j) {
      dA[j] = __expf(dt[j] * An);
      cB[j] = dtu[j] * Bv[j];
      h = fmaf(h, dA[j], cB[j]);
      P *= dA[j];
    }
    // inclusive wave-scan of (P, h) segment pairs; earlier-lane = earlier seq
    float hs = h, Ps = P;
    #pragma unroll
    for (int off = 1; off < 64; off <<= 1) {
      const float hp = __shfl_up(hs, off, 64);
      const float Pp = __shfl_up(Ps, off, 64);
      if (lane >= off) { hs = fmaf(hp, Ps, hs); Ps *= Pp; }
    }
    // exclusive -> h0 for this lane's segment
    float h0 = __shfl_up(hs, 1, 64);
    if (lane == 0) h0 = 0.f;
    // replay with true h0, accumulate y
    #pragma unroll
    for (int j = 0; j < 8; ++j) {
      h0 = fmaf(h0, dA[j], cB[j]);
      y[j] = fmaf(h0, Cv[j], y[j]);
    }
  }

  // D-skip + SiLU(z) gate + write
  const float* zp = xz + (long)(DINNER + d) * NBL + b * SEQ;
  float* yp = (dir ? y_r : y_f) + rbase;
  #pragma unroll
  for (int j = 0; j < 8; ++j) {
    const int lg = lane * 8 + j;
    const int lo = dir ? (SEQ - 1 - lg) : lg;
    const float z = zp[lo];
    yp[lo] = fmaf(Dv, u[j], y[j]) * (z * sigmoidf_(z));
  }
}

// ---------------- y transpose + add + bf16: ybt[n][e] = yf[e][n]+yr[e][n] ----
__global__ __launch_bounds__(256) void ytrans_kernel(
    const float* __restrict__ yf, const float* __restrict__ yr,
    unsigned short* __restrict__ yt) {
  __shared__ unsigned short tile[32][33];
  const int e0 = blockIdx.y * 32, n0 = blockIdx.x * 32;
  const int t = threadIdx.x;
  const int c = t & 31, r8 = t >> 5;
  #pragma unroll
  for (int p = 0; p < 4; ++p) {
    const int e = e0 + p * 8 + r8;
    const float v = yf[(long)e * NBL + n0 + c] + yr[(long)e * NBL + n0 + c];
    tile[p * 8 + r8][c] = f2bf(v);
  }
  __syncthreads();
  #pragma unroll
  for (int p = 0; p < 4; ++p) {
    const int n = n0 + p * 8 + r8;
    yt[(long)n * DINNER + e0 + c] = tile[c][p * 8 + r8];
  }
}

// ---------------- out_proj GEMM, 128x128 tile ----------------
__global__ __launch_bounds__(256) void gemm_out_kernel(
    const unsigned short* __restrict__ A, const unsigned short* __restrict__ B,
    float* __restrict__ C, float* __restrict__ C2) {
  __shared__ unsigned short As[128 * LDK];
  __shared__ unsigned short Bs[128 * LDK];
  const int t = threadIdx.x;
  const int m0 = blockIdx.y * 128, n0 = blockIdx.x * 128;
  const int lane = t & 63;
  const int w = t >> 6;
  const int wr = (w >> 1) * 64, wc = (w & 1) * 64;
  const int fr = lane & 15;
  const int fq = lane >> 4;
  const int K = DINNER;

  f32x4 acc[4][4];
  #pragma unroll
  for (int i = 0; i < 4; ++i)
    #pragma unroll
    for (int j = 0; j < 4; ++j) {
      f32x4 z = {0.f, 0.f, 0.f, 0.f};
      acc[i][j] = z;
    }

  const int srow = t >> 1;
  const int sko = (t & 1) * 16;

  for (int k0 = 0; k0 < K; k0 += 32) {
    if (k0) __syncthreads();
    *(bf16x8*)&As[srow * LDK + sko] =
        *(const bf16x8*)&A[(long)(m0 + srow) * K + k0 + sko];
    *(bf16x8*)&As[srow * LDK + sko + 8] =
        *(const bf16x8*)&A[(long)(m0 + srow) * K + k0 + sko + 8];
    *(bf16x8*)&Bs[srow * LDK + sko] =
        *(const bf16x8*)&B[(long)(n0 + srow) * K + k0 + sko];
    *(bf16x8*)&Bs[srow * LDK + sko + 8] =
        *(const bf16x8*)&B[(long)(n0 + srow) * K + k0 + sko + 8];
    __syncthreads();
    bf16x8 af[4], bg[4];
    #pragma unroll
    for (int i = 0; i < 4; ++i) {
      af[i] = *(const bf16x8*)&As[(wr + i * 16 + fr) * LDK + fq * 8];
      bg[i] = *(const bf16x8*)&Bs[(wc + i * 16 + fr) * LDK + fq * 8];
    }
    #pragma unroll
    for (int i = 0; i < 4; ++i)
      #pragma unroll
      for (int j = 0; j < 4; ++j)
        acc[i][j] = __builtin_amdgcn_mfma_f32_16x16x32_bf16(
            af[i], bg[j], acc[i][j], 0, 0, 0);
  }

  #pragma unroll
  for (int i = 0; i < 4; ++i)
    #pragma unroll
    for (int j = 0; j < 4; ++j)
      #pragma unroll
      for (int r2 = 0; r2 < 4; ++r2) {
        const int m = m0 + wr + i * 16 + fq * 4 + r2;
        const int n = n0 + wc + j * 16 + fr;
        const long addr = (long)n * DMODEL + m;
        C[addr] = acc[i][j][r2];
        C2[addr] = acc[i][j][r2];
      }
}

extern "C" void kernel_launch(void* const* d_in, const int* in_sizes, int n_in,
                              void* d_out, int out_size, void* d_ws, size_t ws_size,
                              hipStream_t stream) {
  (void)in_sizes; (void)n_in; (void)out_size; (void)ws_size;
  const float* x       = (const float*)d_in[0];
  const float* norm_w  = (const float*)d_in[1];
  const float* in_proj = (const float*)d_in[2];
  const float* convw_f = (const float*)d_in[3];
  const float* convb_f = (const float*)d_in[4];
  const float* xpw_f   = (const float*)d_in[5];
  const float* dtw_f   = (const float*)d_in[6];
  const float* dtb_f   = (const float*)d_in[7];
  const float* Alog_f  = (const float*)d_in[8];
  const float* Dsk_f   = (const float*)d_in[9];
  const float* convw_r = (const float*)d_in[10];
  const float* convb_r = (const float*)d_in[11];
  const float* xpw_r   = (const float*)d_in[12];
  const float* dtw_r   = (const float*)d_in[13];
  const float* dtb_r   = (const float*)d_in[14];
  const float* Alog_r  = (const float*)d_in[15];
  const float* Dsk_r   = (const float*)d_in[16];
  const float* out_w   = (const float*)d_in[17];
  const float* normf_w = (const float*)d_in[18];

  float* ws = (float*)d_ws;
  float* residual = ws;  ws += 524288;
  float* xzbuf    = ws;  ws += 2097152;
  float* xconv_f  = ws;  ws += 1048576;
  float* xconv_r  = ws;  ws += 1048576;
  float* xbc_f    = ws;  ws += 32768;
  float* xbc_r    = ws;  ws += 32768;
  float* delta_f  = ws;  ws += 1048576;
  float* delta_r  = ws;  ws += 1048576;
  float* y_f      = ws;  ws += 1048576;
  float* y_r      = ws;  ws += 1048576;
  float* hs       = ws;  ws += 524288;
  float* hnb_f    = ws;  ws += 262144;   // 1024x512 bf16
  float* wbfin_f  = ws;  ws += 2097152;  // 4x2048x512 bf16
  float* wbfout_f = ws;  ws += 1048576;  // 4x512x1024 bf16
  float* ybt_f    = ws;  ws += 524288;   // 1024x1024 bf16
  float* xcT_f    = ws;  ws += 1048576;  // 2 x 1024 x 1024 bf16
  float* dtT_f    = ws;  ws += 32768;    // 2 x 1024 x 32 bf16
  float* xpwb_f_  = ws;  ws += 131072;
  float* xpwb_r_  = ws;  ws += 131072;
  float* dtwb_f_  = ws;  ws += 65536;
  float* dtwb_r_  = ws;  ws += 65536;

  unsigned short* hnb = (unsigned short*)hnb_f;
  unsigned short* wbfin = (unsigned short*)wbfin_f;
  unsigned short* wbfout = (unsigned short*)wbfout_f;
  unsigned short* ybt = (unsigned short*)ybt_f;
  unsigned short* xcT = (unsigned short*)xcT_f;
  unsigned short* dtT = (unsigned short*)dtT_f;
  unsigned short* xpwb_f = (unsigned short*)xpwb_f_;
  unsigned short* xpwb_r = (unsigned short*)xpwb_r_;
  unsigned short* dtwb_f = (unsigned short*)dtwb_f_;
  unsigned short* dtwb_r = (unsigned short*)dtwb_r_;

  float* outp = (float*)d_out;

  wconvert_kernel<<<3456, 256, 0, stream>>>(
      in_proj, out_w, xpw_f, xpw_r, dtw_f, dtw_r,
      wbfin, wbfout, xpwb_f, xpwb_r, dtwb_f, dtwb_r);

  for (int layer = 0; layer < 4; ++layer) {
    addnorm_kernel<<<1024, 256, 0, stream>>>(
        layer == 0 ? x : hs, residual, norm_w + layer * DMODEL,
        nullptr, hnb, layer == 0 ? 1 : 0);
    gemm_in_kernel<<<dim3(16, 16), 256, 0, stream>>>(
        wbfin + (long)layer * 2048 * 512, hnb, xzbuf);
    conv_silu_kernel<<<dim3(32, 32, 2), 256, 0, stream>>>(
        xzbuf, convw_f + layer * DINNER * 4, convb_f + layer * DINNER,
        convw_r + layer * DINNER * 4, convb_r + layer * DINNER,
        xconv_f, xconv_r, xcT);
    xdbl_mfma_kernel<<<dim3(8, 2), 256, 0, stream>>>(
        xpwb_f + (long)layer * 64 * DINNER, xpwb_r + (long)layer * 64 * DINNER,
        xcT, dtT, xbc_f, xbc_r);
    deltam_kernel<<<dim3(8, 8, 2), 256, 0, stream>>>(
        dtwb_f + (long)layer * DINNER * DTRANK, dtwb_r + (long)layer * DINNER * DTRANK,
        dtT, dtb_f + layer * DINNER, dtb_r + layer * DINNER, delta_f, delta_r);
    scan_wave_kernel<<<1024, 256, 0, stream>>>(
        delta_f, delta_r, xconv_f, xconv_r, xbc_f, xbc_r,
        Alog_f + layer * DINNER * DSTATE, Alog_r + layer * DINNER * DSTATE,
        Dsk_f + layer * DINNER, Dsk_r + layer * DINNER,
        xzbuf, y_f, y_r);
    ytrans_kernel<<<dim3(32, 32), 256, 0, stream>>>(y_f, y_r, ybt);
    gemm_out_kernel<<<dim3(8, 4), 256, 0, stream>>>(
        wbfout + (long)layer * 512 * 1024, ybt, hs,
        outp + (long)(1 + layer) * 524288);
  }
  addnorm_kernel<<<1024, 256, 0, stream>>>(hs, residual, normf_w, outp, nullptr, 0);
}

// Round 10
// 392.540 us; speedup vs baseline: 2.7417x; 1.1643x over previous
//
#include <hip/hip_runtime.h>

#define BATCH 2
#define SEQ 512
#define DMODEL 512
#define DINNER 1024
#define DSTATE 16
#define DTRANK 32
#define NBL (BATCH*SEQ)      // 1024
#define EPSV 1e-5f

typedef __attribute__((ext_vector_type(8))) short bf16x8;
typedef __attribute__((ext_vector_type(4))) float f32x4;

static __device__ __forceinline__ float sigmoidf_(float x) {
  return 1.0f / (1.0f + __expf(-x));
}
static __device__ __forceinline__ float softplusf_(float x) {
  return fmaxf(x, 0.0f) + log1pf(__expf(-fabsf(x)));
}
static __device__ __forceinline__ unsigned short f2bf(float x) {
  unsigned int u = __float_as_uint(x);
  unsigned int r = (u + 0x7FFFu + ((u >> 16) & 1u)) >> 16;
  return (unsigned short)r;
}

// ---------------- all-weight fp32 -> bf16 convert (segmented) ----------------
__global__ __launch_bounds__(256) void wconvert_kernel(
    const float* __restrict__ s0, const float* __restrict__ s1,
    const float* __restrict__ s2, const float* __restrict__ s3,
    const float* __restrict__ s4, const float* __restrict__ s5,
    unsigned short* __restrict__ d0, unsigned short* __restrict__ d1,
    unsigned short* __restrict__ d2, unsigned short* __restrict__ d3,
    unsigned short* __restrict__ d4, unsigned short* __restrict__ d5) {
  long i = (long)(blockIdx.x * 256 + threadIdx.x) * 8;
  const float* src; unsigned short* dst;
  if (i < 4194304)      { src = s0; dst = d0; }
  else if (i < 6291456) { src = s1; dst = d1; i -= 4194304; }
  else if (i < 6553600) { src = s2; dst = d2; i -= 6291456; }
  else if (i < 6815744) { src = s3; dst = d3; i -= 6553600; }
  else if (i < 6946816) { src = s4; dst = d4; i -= 6815744; }
  else                  { src = s5; dst = d5; i -= 6946816; }
  const float4 v0 = *(const float4*)&src[i];
  const float4 v1 = *(const float4*)&src[i + 4];
  bf16x8 o;
  o[0] = (short)f2bf(v0.x); o[1] = (short)f2bf(v0.y);
  o[2] = (short)f2bf(v0.z); o[3] = (short)f2bf(v0.w);
  o[4] = (short)f2bf(v1.x); o[5] = (short)f2bf(v1.y);
  o[6] = (short)f2bf(v1.z); o[7] = (short)f2bf(v1.w);
  *(bf16x8*)&dst[i] = o;
}

// ---------------- fused add + RMSNorm ----------------
__global__ __launch_bounds__(256) void addnorm_kernel(
    const float* __restrict__ hs, float* __restrict__ residual,
    const float* __restrict__ w, float* __restrict__ out,
    unsigned short* __restrict__ outb, int first) {
  const int row = blockIdx.x;
  const int t = threadIdx.x;
  const float* hp = hs + (long)row * DMODEL;
  float* rp = residual + (long)row * DMODEL;
  float r0 = hp[t], r1 = hp[t + 256];
  if (!first) { r0 += rp[t]; r1 += rp[t + 256]; }
  rp[t] = r0; rp[t + 256] = r1;
  float ss = r0 * r0 + r1 * r1;
  #pragma unroll
  for (int off = 32; off; off >>= 1) ss += __shfl_xor(ss, off, 64);
  __shared__ float sw[4];
  const int wid = t >> 6, lane = t & 63;
  if (lane == 0) sw[wid] = ss;
  __syncthreads();
  const float tot = sw[0] + sw[1] + sw[2] + sw[3];
  const float scale = rsqrtf(tot * (1.0f / (float)DMODEL) + EPSV);
  const float v0 = r0 * scale * w[t];
  const float v1 = r1 * scale * w[t + 256];
  if (out) {
    out[(long)row * DMODEL + t] = v0;
    out[(long)row * DMODEL + t + 256] = v1;
  }
  if (outb) {
    outb[(long)row * DMODEL + t] = f2bf(v0);
    outb[(long)row * DMODEL + t + 256] = f2bf(v1);
  }
}

#define LDK 40
#define LDK2 72

// ---------------- in_proj GEMM: 128M x 64N, BK=64, reg-prefetch -------------
__global__ __launch_bounds__(256) void gemm_in_kernel(
    const unsigned short* __restrict__ A, const unsigned short* __restrict__ B,
    float* __restrict__ C) {
  __shared__ unsigned short As[128 * LDK2];
  __shared__ unsigned short Bs[64 * LDK2];
  const int t = threadIdx.x;
  const int m0 = blockIdx.y * 128, n0 = blockIdx.x * 64;
  const int lane = t & 63;
  const int w = t >> 6;
  const int wr = (w >> 1) * 64, wc = (w & 1) * 32;
  const int fr = lane & 15;
  const int fq = lane >> 4;
  const int K = DMODEL;

  f32x4 acc[4][2];
  #pragma unroll
  for (int i = 0; i < 4; ++i)
    #pragma unroll
    for (int j = 0; j < 2; ++j) {
      f32x4 z = {0.f, 0.f, 0.f, 0.f};
      acc[i][j] = z;
    }

  const int arow = t >> 1, ako = (t & 1) * 32;   // A: 128 x 64
  const int brow = t >> 2, bko = (t & 3) * 16;   // B: 64 x 64

  bf16x8 pa[4], pb[2];
  #define LOADG_IN(k0_) do {                                              \
    const unsigned short* ap = &A[(long)(m0 + arow) * K + (k0_) + ako];   \
    pa[0] = *(const bf16x8*)ap;        pa[1] = *(const bf16x8*)(ap + 8);  \
    pa[2] = *(const bf16x8*)(ap + 16); pa[3] = *(const bf16x8*)(ap + 24); \
    const unsigned short* bp = &B[(long)(n0 + brow) * K + (k0_) + bko];   \
    pb[0] = *(const bf16x8*)bp;        pb[1] = *(const bf16x8*)(bp + 8);  \
  } while (0)

  LOADG_IN(0);
  for (int k0 = 0; k0 < K; k0 += 64) {
    if (k0) __syncthreads();
    *(bf16x8*)&As[arow * LDK2 + ako]      = pa[0];
    *(bf16x8*)&As[arow * LDK2 + ako + 8]  = pa[1];
    *(bf16x8*)&As[arow * LDK2 + ako + 16] = pa[2];
    *(bf16x8*)&As[arow * LDK2 + ako + 24] = pa[3];
    *(bf16x8*)&Bs[brow * LDK2 + bko]      = pb[0];
    *(bf16x8*)&Bs[brow * LDK2 + bko + 8]  = pb[1];
    __syncthreads();
    if (k0 + 64 < K) LOADG_IN(k0 + 64);
    #pragma unroll
    for (int h = 0; h < 2; ++h) {
      bf16x8 af[4], bg[2];
      #pragma unroll
      for (int i = 0; i < 4; ++i)
        af[i] = *(const bf16x8*)&As[(wr + i * 16 + fr) * LDK2 + h * 32 + fq * 8];
      #pragma unroll
      for (int j = 0; j < 2; ++j)
        bg[j] = *(const bf16x8*)&Bs[(wc + j * 16 + fr) * LDK2 + h * 32 + fq * 8];
      #pragma unroll
      for (int i = 0; i < 4; ++i)
        #pragma unroll
        for (int j = 0; j < 2; ++j)
          acc[i][j] = __builtin_amdgcn_mfma_f32_16x16x32_bf16(
              af[i], bg[j], acc[i][j], 0, 0, 0);
    }
  }
  #undef LOADG_IN

  #pragma unroll
  for (int i = 0; i < 4; ++i)
    #pragma unroll
    for (int j = 0; j < 2; ++j)
      #pragma unroll
      for (int r2 = 0; r2 < 4; ++r2) {
        const int m = m0 + wr + i * 16 + fq * 4 + r2;
        const int n = n0 + wc + j * 16 + fr;
        C[(long)m * NBL + n] = acc[i][j][r2];
      }
}

// ---------------- conv+SiLU + transposed bf16 out (fused xct) ----------------
__global__ __launch_bounds__(256) void conv_silu_kernel(
    const float* __restrict__ xz,
    const float* __restrict__ cw_f, const float* __restrict__ cb_f,
    const float* __restrict__ cw_r, const float* __restrict__ cb_r,
    float* __restrict__ xconv_f, float* __restrict__ xconv_r,
    unsigned short* __restrict__ xcT) {
  __shared__ unsigned short tile[32][33];
  const int dir = blockIdx.z;
  const int n0 = blockIdx.x * 32, d0 = blockIdx.y * 32;
  const int b = n0 >> 9;
  const int l0 = n0 & (SEQ - 1);
  const float* cw = dir ? cw_r : cw_f;
  const float* cb = dir ? cb_r : cb_f;
  float* xconv = dir ? xconv_r : xconv_f;
  unsigned short* dst = xcT + (long)dir * DINNER * NBL;
  const int t = threadIdx.x;
  const int c = t & 31, rr = t >> 5;
  #pragma unroll
  for (int p = 0; p < 4; ++p) {
    const int d = d0 + p * 8 + rr;
    const int l = l0 + c;
    const float* xi = xz + (long)d * NBL + b * SEQ;
    float sum = cb[d];
    #pragma unroll
    for (int k = 0; k < 4; ++k) {
      const int tt = l - 3 + k;
      if (tt >= 0) {
        const int src = dir ? (SEQ - 1 - tt) : tt;
        sum += cw[d * 4 + k] * xi[src];
      }
    }
    const float v = sum * sigmoidf_(sum);
    xconv[(long)d * NBL + n0 + c] = v;
    tile[p * 8 + rr][c] = f2bf(v);
  }
  __syncthreads();
  #pragma unroll
  for (int p = 0; p < 4; ++p) {
    const int n = n0 + p * 8 + rr;
    dst[(long)n * DINNER + d0 + c] = tile[c][p * 8 + rr];
  }
}

// ---------------- x_dbl via MFMA: 64M x 128N, BK=64, reg-prefetch -----------
// rows<32 -> dtT bf16 (dir,n,32); rows>=32 -> xbcT fp32 [slot][NBL].
__global__ __launch_bounds__(256) void xdbl_mfma_kernel(
    const unsigned short* __restrict__ xpwb_f, const unsigned short* __restrict__ xpwb_r,
    const unsigned short* __restrict__ xcT,
    unsigned short* __restrict__ dtT,
    float* __restrict__ xbc_f, float* __restrict__ xbc_r) {
  __shared__ unsigned short As[64 * LDK2];
  __shared__ unsigned short Bs[128 * LDK2];
  const int t = threadIdx.x;
  const int dir = blockIdx.y;
  const int n0 = blockIdx.x * 128;
  const unsigned short* A = dir ? xpwb_r : xpwb_f;
  const unsigned short* B = xcT + (long)dir * DINNER * NBL;
  float* xbc = dir ? xbc_r : xbc_f;
  unsigned short* dtt = dtT + (long)dir * NBL * DTRANK;

  const int lane = t & 63;
  const int w = t >> 6;
  const int fr = lane & 15;
  const int fq = lane >> 4;

  f32x4 acc[4][2];
  #pragma unroll
  for (int i = 0; i < 4; ++i)
    #pragma unroll
    for (int j = 0; j < 2; ++j) {
      f32x4 z = {0.f, 0.f, 0.f, 0.f};
      acc[i][j] = z;
    }

  const int arow = t >> 2, ako = (t & 3) * 16;   // A: 64 x 64
  const int brow = t >> 1, bko = (t & 1) * 32;   // B: 128 x 64

  bf16x8 pa[2], pb[4];
  #define LOADG_XD(k0_) do {                                                   \
    const unsigned short* ap = &A[(long)arow * DINNER + (k0_) + ako];          \
    pa[0] = *(const bf16x8*)ap;        pa[1] = *(const bf16x8*)(ap + 8);       \
    const unsigned short* bp = &B[(long)(n0 + brow) * DINNER + (k0_) + bko];   \
    pb[0] = *(const bf16x8*)bp;        pb[1] = *(const bf16x8*)(bp + 8);       \
    pb[2] = *(const bf16x8*)(bp + 16); pb[3] = *(const bf16x8*)(bp + 24);      \
  } while (0)

  LOADG_XD(0);
  for (int k0 = 0; k0 < DINNER; k0 += 64) {
    if (k0) __syncthreads();
    *(bf16x8*)&As[arow * LDK2 + ako]      = pa[0];
    *(bf16x8*)&As[arow * LDK2 + ako + 8]  = pa[1];
    *(bf16x8*)&Bs[brow * LDK2 + bko]      = pb[0];
    *(bf16x8*)&Bs[brow * LDK2 + bko + 8]  = pb[1];
    *(bf16x8*)&Bs[brow * LDK2 + bko + 16] = pb[2];
    *(bf16x8*)&Bs[brow * LDK2 + bko + 24] = pb[3];
    __syncthreads();
    if (k0 + 64 < DINNER) LOADG_XD(k0 + 64);
    #pragma unroll
    for (int h = 0; h < 2; ++h) {
      bf16x8 af[4], bg[2];
      #pragma unroll
      for (int i = 0; i < 4; ++i)
        af[i] = *(const bf16x8*)&As[(i * 16 + fr) * LDK2 + h * 32 + fq * 8];
      #pragma unroll
      for (int j = 0; j < 2; ++j)
        bg[j] = *(const bf16x8*)&Bs[(w * 32 + j * 16 + fr) * LDK2 + h * 32 + fq * 8];
      #pragma unroll
      for (int i = 0; i < 4; ++i)
        #pragma unroll
        for (int j = 0; j < 2; ++j)
          acc[i][j] = __builtin_amdgcn_mfma_f32_16x16x32_bf16(
              af[i], bg[j], acc[i][j], 0, 0, 0);
    }
  }
  #undef LOADG_XD

  #pragma unroll
  for (int i = 0; i < 4; ++i)
    #pragma unroll
    for (int j = 0; j < 2; ++j)
      #pragma unroll
      for (int r2 = 0; r2 < 4; ++r2) {
        const int m = i * 16 + fq * 4 + r2;
        const int n = n0 + w * 32 + j * 16 + fr;
        const float v = acc[i][j][r2];
        if (m < DTRANK) dtt[(long)n * DTRANK + m] = f2bf(v);
        else xbc[(long)(m - 32) * NBL + n] = v;   // slot-major
      }
}

// ---------------- delta via MFMA: softplus(dtw @ dt + dtb) ----------------
__global__ __launch_bounds__(256) void deltam_kernel(
    const unsigned short* __restrict__ dtwb_f, const unsigned short* __restrict__ dtwb_r,
    const unsigned short* __restrict__ dtT,
    const float* __restrict__ dtb_f, const float* __restrict__ dtb_r,
    float* __restrict__ delta_f, float* __restrict__ delta_r) {
  __shared__ unsigned short As[128 * LDK];
  __shared__ unsigned short Bs[128 * LDK];
  const int t = threadIdx.x;
  const int dir = blockIdx.z;
  const unsigned short* A = dir ? dtwb_r : dtwb_f;
  const unsigned short* B = dtT + (long)dir * NBL * DTRANK;
  const float* dtb = dir ? dtb_r : dtb_f;
  float* dl = dir ? delta_r : delta_f;
  const int m0 = blockIdx.y * 128, n0 = blockIdx.x * 128;
  const int lane = t & 63;
  const int w = t >> 6;
  const int wr = (w >> 1) * 64, wc = (w & 1) * 64;
  const int fr = lane & 15;
  const int fq = lane >> 4;

  const int srow = t >> 1;
  const int sko = (t & 1) * 16;
  *(bf16x8*)&As[srow * LDK + sko] =
      *(const bf16x8*)&A[(long)(m0 + srow) * DTRANK + sko];
  *(bf16x8*)&As[srow * LDK + sko + 8] =
      *(const bf16x8*)&A[(long)(m0 + srow) * DTRANK + sko + 8];
  *(bf16x8*)&Bs[srow * LDK + sko] =
      *(const bf16x8*)&B[(long)(n0 + srow) * DTRANK + sko];
  *(bf16x8*)&Bs[srow * LDK + sko + 8] =
      *(const bf16x8*)&B[(long)(n0 + srow) * DTRANK + sko + 8];
  __syncthreads();

  bf16x8 af[4], bg[4];
  #pragma unroll
  for (int i = 0; i < 4; ++i) {
    af[i] = *(const bf16x8*)&As[(wr + i * 16 + fr) * LDK + fq * 8];
    bg[i] = *(const bf16x8*)&Bs[(wc + i * 16 + fr) * LDK + fq * 8];
  }
  f32x4 acc[4][4];
  #pragma unroll
  for (int i = 0; i < 4; ++i)
    #pragma unroll
    for (int j = 0; j < 4; ++j) {
      f32x4 z = {0.f, 0.f, 0.f, 0.f};
      acc[i][j] = __builtin_amdgcn_mfma_f32_16x16x32_bf16(af[i], bg[j], z, 0, 0, 0);
    }

  #pragma unroll
  for (int i = 0; i < 4; ++i) {
    const int m = m0 + wr + i * 16 + fq * 4;
    #pragma unroll
    for (int r2 = 0; r2 < 4; ++r2) {
      const float bias = dtb[m + r2];
      #pragma unroll
      for (int j = 0; j < 4; ++j) {
        const int n = n0 + wc + j * 16 + fr;
        dl[(long)(m + r2) * NBL + n] = softplusf_(acc[i][j][r2] + bias);
      }
    }
  }
}

// ---------------- selective scan: one wave per row, lane owns 8 steps -------
__global__ __launch_bounds__(256) void scan_wave_kernel(
    const float* __restrict__ delta_f, const float* __restrict__ delta_r,
    const float* __restrict__ xconv_f, const float* __restrict__ xconv_r,
    const float* __restrict__ xbc_f, const float* __restrict__ xbc_r,
    const float* __restrict__ Alog_f, const float* __restrict__ Alog_r,
    const float* __restrict__ Dsk_f, const float* __restrict__ Dsk_r,
    const float* __restrict__ xz,
    float* __restrict__ y_f, float* __restrict__ y_r) {
  const int t = threadIdx.x;
  const int wv = t >> 6;
  const int lane = t & 63;
  const int row = blockIdx.x * 4 + wv;          // 0..4095
  const int dir = row >> 11, b = (row >> 10) & 1, d = row & 1023;

  const long rbase = (long)d * NBL + b * SEQ;
  const float* dp = (dir ? delta_r : delta_f) + rbase + lane * 8;
  const float* up = (dir ? xconv_r : xconv_f) + rbase + lane * 8;
  const float* bct = (dir ? xbc_r : xbc_f) + b * SEQ + lane * 8;
  const float* Alog = (dir ? Alog_r : Alog_f) + d * DSTATE;
  const float Dv = (dir ? Dsk_r : Dsk_f)[d];

  float dt[8], u[8], dtu[8], y[8];
  {
    const float4 a0 = *(const float4*)&dp[0];
    const float4 a1 = *(const float4*)&dp[4];
    dt[0] = a0.x; dt[1] = a0.y; dt[2] = a0.z; dt[3] = a0.w;
    dt[4] = a1.x; dt[5] = a1.y; dt[6] = a1.z; dt[7] = a1.w;
    const float4 b0 = *(const float4*)&up[0];
    const float4 b1 = *(const float4*)&up[4];
    u[0] = b0.x; u[1] = b0.y; u[2] = b0.z; u[3] = b0.w;
    u[4] = b1.x; u[5] = b1.y; u[6] = b1.z; u[7] = b1.w;
  }
  #pragma unroll
  for (int j = 0; j < 8; ++j) { dtu[j] = dt[j] * u[j]; y[j] = 0.f; }

  for (int n = 0; n < DSTATE; ++n) {
    const float An = -__expf(Alog[n]);
    float Bv[8], Cv[8], dA[8], cB[8];
    {
      const float* bp = bct + (long)n * NBL;
      const float* cp = bct + (long)(DSTATE + n) * NBL;
      const float4 b0 = *(const float4*)&bp[0];
      const float4 b1 = *(const float4*)&bp[4];
      Bv[0] = b0.x; Bv[1] = b0.y; Bv[2] = b0.z; Bv[3] = b0.w;
      Bv[4] = b1.x; Bv[5] = b1.y; Bv[6] = b1.z; Bv[7] = b1.w;
      const float4 c0 = *(const float4*)&cp[0];
      const float4 c1 = *(const float4*)&cp[4];
      Cv[0] = c0.x; Cv[1] = c0.y; Cv[2] = c0.z; Cv[3] = c0.w;
      Cv[4] = c1.x; Cv[5] = c1.y; Cv[6] = c1.z; Cv[7] = c1.w;
    }
    float h = 0.f, P = 1.f;
    #pragma unroll
    for (int j = 0; j < 8; ++j) {
      dA[j] = __expf(dt[j] * An);
      cB[j] = dtu[j] * Bv[j];
      h = fmaf(h, dA[j], cB[j]);
      P *= dA[j];
    }
    float hs = h, Ps = P;
    #pragma unroll
    for (int off = 1; off < 64; off <<= 1) {
      const float hp = __shfl_up(hs, off, 64);
      const float Pp = __shfl_up(Ps, off, 64);
      if (lane >= off) { hs = fmaf(hp, Ps, hs); Ps *= Pp; }
    }
    float h0 = __shfl_up(hs, 1, 64);
    if (lane == 0) h0 = 0.f;
    #pragma unroll
    for (int j = 0; j < 8; ++j) {
      h0 = fmaf(h0, dA[j], cB[j]);
      y[j] = fmaf(h0, Cv[j], y[j]);
    }
  }

  const float* zp = xz + (long)(DINNER + d) * NBL + b * SEQ;
  float* yp = (dir ? y_r : y_f) + rbase;
  #pragma unroll
  for (int j = 0; j < 8; ++j) {
    const int lg = lane * 8 + j;
    const int lo = dir ? (SEQ - 1 - lg) : lg;
    const float z = zp[lo];
    yp[lo] = fmaf(Dv, u[j], y[j]) * (z * sigmoidf_(z));
  }
}

// ---------------- y transpose + add + bf16 ----------------
__global__ __launch_bounds__(256) void ytrans_kernel(
    const float* __restrict__ yf, const float* __restrict__ yr,
    unsigned short* __restrict__ yt) {
  __shared__ unsigned short tile[32][33];
  const int e0 = blockIdx.y * 32, n0 = blockIdx.x * 32;
  const int t = threadIdx.x;
  const int c = t & 31, r8 = t >> 5;
  #pragma unroll
  for (int p = 0; p < 4; ++p) {
    const int e = e0 + p * 8 + r8;
    const float v = yf[(long)e * NBL + n0 + c] + yr[(long)e * NBL + n0 + c];
    tile[p * 8 + r8][c] = f2bf(v);
  }
  __syncthreads();
  #pragma unroll
  for (int p = 0; p < 4; ++p) {
    const int n = n0 + p * 8 + r8;
    yt[(long)n * DINNER + e0 + c] = tile[c][p * 8 + r8];
  }
}

// ---------------- out_proj GEMM: 128x128, BK=64, reg-prefetch ---------------
__global__ __launch_bounds__(256) void gemm_out_kernel(
    const unsigned short* __restrict__ A, const unsigned short* __restrict__ B,
    float* __restrict__ C, float* __restrict__ C2) {
  __shared__ unsigned short As[128 * LDK2];
  __shared__ unsigned short Bs[128 * LDK2];
  const int t = threadIdx.x;
  const int m0 = blockIdx.y * 128, n0 = blockIdx.x * 128;
  const int lane = t & 63;
  const int w = t >> 6;
  const int wr = (w >> 1) * 64, wc = (w & 1) * 64;
  const int fr = lane & 15;
  const int fq = lane >> 4;
  const int K = DINNER;

  f32x4 acc[4][4];
  #pragma unroll
  for (int i = 0; i < 4; ++i)
    #pragma unroll
    for (int j = 0; j < 4; ++j) {
      f32x4 z = {0.f, 0.f, 0.f, 0.f};
      acc[i][j] = z;
    }

  const int srow = t >> 1, sko = (t & 1) * 32;   // both: 128 x 64

  bf16x8 pa[4], pb[4];
  #define LOADG_OUT(k0_) do {                                              \
    const unsigned short* ap = &A[(long)(m0 + srow) * K + (k0_) + sko];    \
    pa[0] = *(const bf16x8*)ap;        pa[1] = *(const bf16x8*)(ap + 8);   \
    pa[2] = *(const bf16x8*)(ap + 16); pa[3] = *(const bf16x8*)(ap + 24);  \
    const unsigned short* bp = &B[(long)(n0 + srow) * K + (k0_) + sko];    \
    pb[0] = *(const bf16x8*)bp;        pb[1] = *(const bf16x8*)(bp + 8);   \
    pb[2] = *(const bf16x8*)(bp + 16); pb[3] = *(const bf16x8*)(bp + 24);  \
  } while (0)

  LOADG_OUT(0);
  for (int k0 = 0; k0 < K; k0 += 64) {
    if (k0) __syncthreads();
    *(bf16x8*)&As[srow * LDK2 + sko]      = pa[0];
    *(bf16x8*)&As[srow * LDK2 + sko + 8]  = pa[1];
    *(bf16x8*)&As[srow * LDK2 + sko + 16] = pa[2];
    *(bf16x8*)&As[srow * LDK2 + sko + 24] = pa[3];
    *(bf16x8*)&Bs[srow * LDK2 + sko]      = pb[0];
    *(bf16x8*)&Bs[srow * LDK2 + sko + 8]  = pb[1];
    *(bf16x8*)&Bs[srow * LDK2 + sko + 16] = pb[2];
    *(bf16x8*)&Bs[srow * LDK2 + sko + 24] = pb[3];
    __syncthreads();
    if (k0 + 64 < K) LOADG_OUT(k0 + 64);
    #pragma unroll
    for (int h = 0; h < 2; ++h) {
      bf16x8 af[4], bg[4];
      #pragma unroll
      for (int i = 0; i < 4; ++i) {
        af[i] = *(const bf16x8*)&As[(wr + i * 16 + fr) * LDK2 + h * 32 + fq * 8];
        bg[i] = *(const bf16x8*)&Bs[(wc + i * 16 + fr) * LDK2 + h * 32 + fq * 8];
      }
      #pragma unroll
      for (int i = 0; i < 4; ++i)
        #pragma unroll
        for (int j = 0; j < 4; ++j)
          acc[i][j] = __builtin_amdgcn_mfma_f32_16x16x32_bf16(
              af[i], bg[j], acc[i][j], 0, 0, 0);
    }
  }
  #undef LOADG_OUT

  #pragma unroll
  for (int i = 0; i < 4; ++i)
    #pragma unroll
    for (int j = 0; j < 4; ++j)
      #pragma unroll
      for (int r2 = 0; r2 < 4; ++r2) {
        const int m = m0 + wr + i * 16 + fq * 4 + r2;
        const int n = n0 + wc + j * 16 + fr;
        const long addr = (long)n * DMODEL + m;
        C[addr] = acc[i][j][r2];
        C2[addr] = acc[i][j][r2];
      }
}

extern "C" void kernel_launch(void* const* d_in, const int* in_sizes, int n_in,
                              void* d_out, int out_size, void* d_ws, size_t ws_size,
                              hipStream_t stream) {
  (void)in_sizes; (void)n_in; (void)out_size; (void)ws_size;
  const float* x       = (const float*)d_in[0];
  const float* norm_w  = (const float*)d_in[1];
  const float* in_proj = (const float*)d_in[2];
  const float* convw_f = (const float*)d_in[3];
  const float* convb_f = (const float*)d_in[4];
  const float* xpw_f   = (const float*)d_in[5];
  const float* dtw_f   = (const float*)d_in[6];
  const float* dtb_f   = (const float*)d_in[7];
  const float* Alog_f  = (const float*)d_in[8];
  const float* Dsk_f   = (const float*)d_in[9];
  const float* convw_r = (const float*)d_in[10];
  const float* convb_r = (const float*)d_in[11];
  const float* xpw_r   = (const float*)d_in[12];
  const float* dtw_r   = (const float*)d_in[13];
  const float* dtb_r   = (const float*)d_in[14];
  const float* Alog_r  = (const float*)d_in[15];
  const float* Dsk_r   = (const float*)d_in[16];
  const float* out_w   = (const float*)d_in[17];
  const float* normf_w = (const float*)d_in[18];

  float* ws = (float*)d_ws;
  float* residual = ws;  ws += 524288;
  float* xzbuf    = ws;  ws += 2097152;
  float* xconv_f  = ws;  ws += 1048576;
  float* xconv_r  = ws;  ws += 1048576;
  float* xbc_f    = ws;  ws += 32768;
  float* xbc_r    = ws;  ws += 32768;
  float* delta_f  = ws;  ws += 1048576;
  float* delta_r  = ws;  ws += 1048576;
  float* y_f      = ws;  ws += 1048576;
  float* y_r      = ws;  ws += 1048576;
  float* hs       = ws;  ws += 524288;
  float* hnb_f    = ws;  ws += 262144;   // 1024x512 bf16
  float* wbfin_f  = ws;  ws += 2097152;  // 4x2048x512 bf16
  float* wbfout_f = ws;  ws += 1048576;  // 4x512x1024 bf16
  float* ybt_f    = ws;  ws += 524288;   // 1024x1024 bf16
  float* xcT_f    = ws;  ws += 1048576;  // 2 x 1024 x 1024 bf16
  float* dtT_f    = ws;  ws += 32768;    // 2 x 1024 x 32 bf16
  float* xpwb_f_  = ws;  ws += 131072;
  float* xpwb_r_  = ws;  ws += 131072;
  float* dtwb_f_  = ws;  ws += 65536;
  float* dtwb_r_  = ws;  ws += 65536;

  unsigned short* hnb = (unsigned short*)hnb_f;
  unsigned short* wbfin = (unsigned short*)wbfin_f;
  unsigned short* wbfout = (unsigned short*)wbfout_f;
  unsigned short* ybt = (unsigned short*)ybt_f;
  unsigned short* xcT = (unsigned short*)xcT_f;
  unsigned short* dtT = (unsigned short*)dtT_f;
  unsigned short* xpwb_f = (unsigned short*)xpwb_f_;
  unsigned short* xpwb_r = (unsigned short*)xpwb_r_;
  unsigned short* dtwb_f = (unsigned short*)dtwb_f_;
  unsigned short* dtwb_r = (unsigned short*)dtwb_r_;

  float* outp = (float*)d_out;

  wconvert_kernel<<<3456, 256, 0, stream>>>(
      in_proj, out_w, xpw_f, xpw_r, dtw_f, dtw_r,
      wbfin, wbfout, xpwb_f, xpwb_r, dtwb_f, dtwb_r);

  for (int layer = 0; layer < 4; ++layer) {
    addnorm_kernel<<<1024, 256, 0, stream>>>(
        layer == 0 ? x : hs, residual, norm_w + layer * DMODEL,
        nullptr, hnb, layer == 0 ? 1 : 0);
    gemm_in_kernel<<<dim3(16, 16), 256, 0, stream>>>(
        wbfin + (long)layer * 2048 * 512, hnb, xzbuf);
    conv_silu_kernel<<<dim3(32, 32, 2), 256, 0, stream>>>(
        xzbuf, convw_f + layer * DINNER * 4, convb_f + layer * DINNER,
        convw_r + layer * DINNER * 4, convb_r + layer * DINNER,
        xconv_f, xconv_r, xcT);
    xdbl_mfma_kernel<<<dim3(8, 2), 256, 0, stream>>>(
        xpwb_f + (long)layer * 64 * DINNER, xpwb_r + (long)layer * 64 * DINNER,
        xcT, dtT, xbc_f, xbc_r);
    deltam_kernel<<<dim3(8, 8, 2), 256, 0, stream>>>(
        dtwb_f + (long)layer * DINNER * DTRANK, dtwb_r + (long)layer * DINNER * DTRANK,
        dtT, dtb_f + layer * DINNER, dtb_r + layer * DINNER, delta_f, delta_r);
    scan_wave_kernel<<<1024, 256, 0, stream>>>(
        delta_f, delta_r, xconv_f, xconv_r, xbc_f, xbc_r,
        Alog_f + layer * DINNER * DSTATE, Alog_r + layer * DINNER * DSTATE,
        Dsk_f + layer * DINNER, Dsk_r + layer * DINNER,
        xzbuf, y_f, y_r);
    ytrans_kernel<<<dim3(32, 32), 256, 0, stream>>>(y_f, y_r, ybt);
    gemm_out_kernel<<<dim3(8, 4), 256, 0, stream>>>(
        wbfout + (long)layer * 512 * 1024, ybt, hs,
        outp + (long)(1 + layer) * 524288);
  }
  addnorm_kernel<<<1024, 256, 0, stream>>>(hs, residual, normf_w, outp, nullptr, 0);
}